// Round 1
// 1934.606 us; speedup vs baseline: 2.3007x; 2.3007x over previous
//
#include <hip/hip_runtime.h>
#include <hip/hip_bf16.h>

// Problem constants (MultiHeadAttention_14508399526473)
// Inputs fp32 (per reference). Outputs fp32: [out (B,S,D) | attn (B,H,S,S)].
#define B_ 2
#define S_ 2048
#define D_ 1024
#define H_ 16
#define DH_ 64
#define EPS_ 1e-6f

// ---------------------------------------------------------------------------
// Tiled GEMM: C[M,N] = A[M,K] @ W[K,N] + bias[N] (+ residual[M,N] optional)
// All fp32. Block 256, 64x64 tile, 4x4 per thread, K-chunks of 16.
// M,N,K % 64 == 0.
// ---------------------------------------------------------------------------
__global__ __launch_bounds__(256) void gemm_bias_kernel(
    const float* __restrict__ A, const float* __restrict__ W,
    const float* __restrict__ bias, const float* __restrict__ residual,
    float* __restrict__ C, int M, int N, int K)
{
    __shared__ float As[64][17];   // [row][k], pad to kill bank conflicts
    __shared__ float Ws[16][64];   // [k][col]

    const int tid = threadIdx.x;
    const int tx = tid & 15, ty = tid >> 4;
    const int row0 = blockIdx.y * 64;
    const int col0 = blockIdx.x * 64;

    float c[4][4];
#pragma unroll
    for (int i = 0; i < 4; ++i)
#pragma unroll
        for (int j = 0; j < 4; ++j) c[i][j] = 0.f;

    for (int k0 = 0; k0 < K; k0 += 16) {
#pragma unroll
        for (int l = 0; l < 4; ++l) {           // A tile: 64 rows x 16 k
            int idx = tid + l * 256;            // 0..1023
            int r = idx >> 4, kk = idx & 15;
            As[r][kk] = A[(size_t)(row0 + r) * K + k0 + kk];
        }
#pragma unroll
        for (int l = 0; l < 4; ++l) {           // W tile: 16 k x 64 cols
            int idx = tid + l * 256;
            int kk = idx >> 6, cc = idx & 63;
            Ws[kk][cc] = W[(size_t)(k0 + kk) * N + col0 + cc];
        }
        __syncthreads();
#pragma unroll
        for (int kk = 0; kk < 16; ++kk) {
            float a[4], w[4];
#pragma unroll
            for (int i = 0; i < 4; ++i) a[i] = As[ty + i * 16][kk];
#pragma unroll
            for (int j = 0; j < 4; ++j) w[j] = Ws[kk][tx + j * 16];
#pragma unroll
            for (int i = 0; i < 4; ++i)
#pragma unroll
                for (int j = 0; j < 4; ++j) c[i][j] += a[i] * w[j];
        }
        __syncthreads();
    }

#pragma unroll
    for (int i = 0; i < 4; ++i) {
        int r = row0 + ty + i * 16;
#pragma unroll
        for (int j = 0; j < 4; ++j) {
            int cc = col0 + tx + j * 16;
            float v = c[i][j] + bias[cc];
            if (residual) v += residual[(size_t)r * N + cc];
            C[(size_t)r * N + cc] = v;
        }
    }
}

// ---------------------------------------------------------------------------
// QK^T: logits[bh, q, k] = 0.125 * sum_d Q[b,q,h*64+d] * K[b,k,h*64+d]
// One block per lower-triangular 64x64 tile per (b,h). Upper tiles skipped
// (their attn values are written as exact zeros by softmax_kernel).
// Diagonal-tile entries above the diagonal are garbage; softmax overwrites.
// ---------------------------------------------------------------------------
__global__ __launch_bounds__(256) void qk_kernel(
    const float* __restrict__ Q, const float* __restrict__ Km,
    float* __restrict__ logits)
{
    const int tk = blockIdx.x, tq = blockIdx.y;
    if (tk > tq) return;
    const int bh = blockIdx.z;
    const int b = bh >> 4, h = bh & 15;
    const int tid = threadIdx.x;
    const int tx = tid & 15, ty = tid >> 4;

    __shared__ float Qs[64][17];
    __shared__ float Ks[64][17];

    const size_t base = ((size_t)b * S_) * D_ + (size_t)h * DH_;
    const float* Aq = Q  + base + (size_t)(tq * 64) * D_;  // 64 q-rows, stride D
    const float* Ak = Km + base + (size_t)(tk * 64) * D_;  // 64 k-rows, stride D

    float c[4][4];
#pragma unroll
    for (int i = 0; i < 4; ++i)
#pragma unroll
        for (int j = 0; j < 4; ++j) c[i][j] = 0.f;

    for (int d0 = 0; d0 < DH_; d0 += 16) {
#pragma unroll
        for (int l = 0; l < 4; ++l) {           // 64 rows x 16 d each
            int idx = tid + l * 256;
            int r = idx >> 4, kk = idx & 15;
            Qs[r][kk] = Aq[(size_t)r * D_ + d0 + kk];
            Ks[r][kk] = Ak[(size_t)r * D_ + d0 + kk];
        }
        __syncthreads();
#pragma unroll
        for (int kk = 0; kk < 16; ++kk) {
            float a[4], w[4];
#pragma unroll
            for (int i = 0; i < 4; ++i) a[i] = Qs[ty + i * 16][kk];
#pragma unroll
            for (int j = 0; j < 4; ++j) w[j] = Ks[tx + j * 16][kk];
#pragma unroll
            for (int i = 0; i < 4; ++i)
#pragma unroll
                for (int j = 0; j < 4; ++j) c[i][j] += a[i] * w[j];
        }
        __syncthreads();
    }

    float* orow = logits + ((size_t)bh * S_ + (size_t)(tq * 64)) * S_ + tk * 64;
#pragma unroll
    for (int i = 0; i < 4; ++i) {
        int r = ty + i * 16;
#pragma unroll
        for (int j = 0; j < 4; ++j)
            orow[(size_t)r * S_ + tx + j * 16] = c[i][j] * 0.125f;
    }
}

// ---------------------------------------------------------------------------
// Row softmax over logits, in place (the buffer IS the attn output).
// One block per (q-row, bh). Row cached in LDS; causal tail written as 0
// (matches exp(-1e4 - m) fp32 underflow in the reference).
// ---------------------------------------------------------------------------
__global__ __launch_bounds__(256) void softmax_kernel(float* __restrict__ attn)
{
    const int qi = blockIdx.x;
    const int bh = blockIdx.y;
    const int tid = threadIdx.x;
    const int lane = tid & 63, wid = tid >> 6;
    float* row = attn + ((size_t)bh * S_ + qi) * S_;
    const int len = qi + 1;

    __shared__ float lg[S_];
    __shared__ float red[8];

    float lmax = -INFINITY;
    for (int j = tid; j < len; j += 256) {
        float v = row[j];
        lg[j] = v;
        lmax = fmaxf(lmax, v);
    }
#pragma unroll
    for (int o = 32; o > 0; o >>= 1) lmax = fmaxf(lmax, __shfl_xor(lmax, o));
    if (lane == 0) red[wid] = lmax;
    __syncthreads();
    const float m = fmaxf(fmaxf(red[0], red[1]), fmaxf(red[2], red[3]));

    float lsum = 0.f;
    for (int j = tid; j < len; j += 256) {
        float e = __expf(lg[j] - m);
        lg[j] = e;
        lsum += e;
    }
#pragma unroll
    for (int o = 32; o > 0; o >>= 1) lsum += __shfl_xor(lsum, o);
    if (lane == 0) red[4 + wid] = lsum;
    __syncthreads();
    const float inv = 1.f / (red[4] + red[5] + red[6] + red[7]);

    float4* row4 = (float4*)row;
    for (int j4 = tid; j4 < S_ / 4; j4 += 256) {
        int j = j4 * 4;
        float4 o;
        o.x = (j     < len) ? lg[j]     * inv : 0.f;
        o.y = (j + 1 < len) ? lg[j + 1] * inv : 0.f;
        o.z = (j + 2 < len) ? lg[j + 2] * inv : 0.f;
        o.w = (j + 3 < len) ? lg[j + 3] * inv : 0.f;
        row4[j4] = o;
    }
}

// ---------------------------------------------------------------------------
// PV: ctx[b, q, h*64+d] = sum_k attn[bh,q,k] * V[b,k,h*64+d]
// One block per 64-row q-tile per (b,h); K-extent (tq+1)*64 (causal skip —
// attn is exactly 0 beyond the diagonal tile, so nothing is lost).
// ---------------------------------------------------------------------------
__global__ __launch_bounds__(256) void pv_kernel(
    const float* __restrict__ P, const float* __restrict__ V,
    float* __restrict__ ctx)
{
    const int tq = blockIdx.x;
    const int bh = blockIdx.y;
    const int b = bh >> 4, h = bh & 15;
    const int tid = threadIdx.x;
    const int tx = tid & 15, ty = tid >> 4;

    __shared__ float As[64][17];   // attn tile: 64 q-rows x 16 k
    __shared__ float Ws[16][64];   // V tile: 16 k x 64 d

    const float* A = P + ((size_t)bh * S_ + (size_t)(tq * 64)) * S_; // stride S
    const float* W = V + ((size_t)b * S_) * D_ + h * DH_;            // stride D

    float c[4][4];
#pragma unroll
    for (int i = 0; i < 4; ++i)
#pragma unroll
        for (int j = 0; j < 4; ++j) c[i][j] = 0.f;

    const int Kext = (tq + 1) * 64;
    for (int k0 = 0; k0 < Kext; k0 += 16) {
#pragma unroll
        for (int l = 0; l < 4; ++l) {
            int idx = tid + l * 256;
            int r = idx >> 4, kk = idx & 15;
            As[r][kk] = A[(size_t)r * S_ + k0 + kk];
        }
#pragma unroll
        for (int l = 0; l < 4; ++l) {
            int idx = tid + l * 256;
            int kk = idx >> 6, cc = idx & 63;
            Ws[kk][cc] = W[(size_t)(k0 + kk) * D_ + cc];
        }
        __syncthreads();
#pragma unroll
        for (int kk = 0; kk < 16; ++kk) {
            float a[4], w[4];
#pragma unroll
            for (int i = 0; i < 4; ++i) a[i] = As[ty + i * 16][kk];
#pragma unroll
            for (int j = 0; j < 4; ++j) w[j] = Ws[kk][tx + j * 16];
#pragma unroll
            for (int i = 0; i < 4; ++i)
#pragma unroll
                for (int j = 0; j < 4; ++j) c[i][j] += a[i] * w[j];
        }
        __syncthreads();
    }

    float* C = ctx + ((size_t)b * S_ + (size_t)(tq * 64)) * D_ + h * DH_;
#pragma unroll
    for (int i = 0; i < 4; ++i) {
        int r = ty + i * 16;
#pragma unroll
        for (int j = 0; j < 4; ++j)
            C[(size_t)r * D_ + tx + j * 16] = c[i][j];
    }
}

// ---------------------------------------------------------------------------
// Row LayerNorm: one block per row of [B*S, D], fp32 in, fp32 out.
// ---------------------------------------------------------------------------
__global__ __launch_bounds__(256) void ln_kernel(
    const float* __restrict__ X, const float* __restrict__ gamma,
    const float* __restrict__ beta, float* __restrict__ out)
{
    const int row = blockIdx.x;
    const int tid = threadIdx.x;
    const float* x = X + (size_t)row * D_;
    __shared__ float red[256];

    float s = 0.f;
    for (int i = tid; i < D_; i += 256) s += x[i];
    red[tid] = s;
    __syncthreads();
    for (int t = 128; t > 0; t >>= 1) {
        if (tid < t) red[tid] += red[tid + t];
        __syncthreads();
    }
    const float mu = red[0] * (1.f / D_);
    __syncthreads();

    float v = 0.f;
    for (int i = tid; i < D_; i += 256) {
        float t = x[i] - mu;
        v += t * t;
    }
    red[tid] = v;
    __syncthreads();
    for (int t = 128; t > 0; t >>= 1) {
        if (tid < t) red[tid] += red[tid + t];
        __syncthreads();
    }
    const float r = rsqrtf(red[0] * (1.f / D_) + EPS_);

    for (int i = tid; i < D_; i += 256) {
        float o = (x[i] - mu) * r * gamma[i] + beta[i];
        out[(size_t)row * D_ + i] = o;
    }
}

// ---------------------------------------------------------------------------
extern "C" void kernel_launch(void* const* d_in, const int* in_sizes, int n_in,
                              void* d_out, int out_size, void* d_ws, size_t ws_size,
                              hipStream_t stream)
{
    const float* query = (const float*)d_in[0];
    const float* key   = (const float*)d_in[1];
    const float* value = (const float*)d_in[2];
    // d_in[3] = mask (causal) — applied structurally (lower-tri tiles + zero tail)
    const float* wq_w = (const float*)d_in[4];
    const float* wq_b = (const float*)d_in[5];
    const float* wk_w = (const float*)d_in[6];
    const float* wk_b = (const float*)d_in[7];
    const float* wv_w = (const float*)d_in[8];
    const float* wv_b = (const float*)d_in[9];
    const float* wo_w = (const float*)d_in[10];
    const float* wo_b = (const float*)d_in[11];
    const float* ln_g = (const float*)d_in[12];
    const float* ln_b = (const float*)d_in[13];

    float* out_f  = (float*)d_out;                        // (B,S,D)
    float* attn_f = out_f + (size_t)B_ * S_ * D_;         // (B,H,S,S) — also the
                                                          // logits scratch (in-place)

    const size_t MAT = (size_t)B_ * S_ * D_;  // 4,194,304 floats (16 MB)
    float* ws  = (float*)d_ws;
    float* Qf  = ws;            // dead after qk; reused for pre-LN
    float* Kf  = ws + MAT;
    float* Vf  = ws + 2 * MAT;
    float* ctx = ws + 3 * MAT;
    float* pre = Qf;            // alias: pre-LN buffer

    const int M = B_ * S_, N = D_, K = D_;
    dim3 ggrd(N / 64, M / 64);

    // Projections
    hipLaunchKernelGGL(gemm_bias_kernel, ggrd, dim3(256), 0, stream,
                       query, wq_w, wq_b, (const float*)nullptr, Qf, M, N, K);
    hipLaunchKernelGGL(gemm_bias_kernel, ggrd, dim3(256), 0, stream,
                       key, wk_w, wk_b, (const float*)nullptr, Kf, M, N, K);
    hipLaunchKernelGGL(gemm_bias_kernel, ggrd, dim3(256), 0, stream,
                       value, wv_w, wv_b, (const float*)nullptr, Vf, M, N, K);

    // QK^T (lower-tri 64x64 tiles) -> logits in attn buffer
    hipLaunchKernelGGL(qk_kernel, dim3(S_ / 64, S_ / 64, B_ * H_), dim3(256),
                       0, stream, Qf, Kf, attn_f);

    // Row softmax in place (writes normalized probs + zero causal tail)
    hipLaunchKernelGGL(softmax_kernel, dim3(S_, B_ * H_), dim3(256), 0, stream,
                       attn_f);

    // PV -> ctx (B,S,D)
    hipLaunchKernelGGL(pv_kernel, dim3(S_ / 64, B_ * H_), dim3(256), 0, stream,
                       attn_f, Vf, ctx);

    // Output projection + residual, then LayerNorm
    hipLaunchKernelGGL(gemm_bias_kernel, ggrd, dim3(256), 0, stream,
                       ctx, wo_w, wo_b, query, pre, M, N, K);

    hipLaunchKernelGGL(ln_kernel, dim3(B_ * S_), dim3(256), 0, stream,
                       pre, ln_g, ln_b, out_f);
}

// Round 2
// 1572.995 us; speedup vs baseline: 2.8296x; 1.2299x over previous
//
#include <hip/hip_runtime.h>
#include <hip/hip_bf16.h>

// Problem constants (MultiHeadAttention_14508399526473)
// Inputs fp32 (per reference). Outputs fp32: [out (B,S,D) | attn (B,H,S,S)].
#define B_ 2
#define S_ 2048
#define D_ 1024
#define H_ 16
#define DH_ 64
#define EPS_ 1e-6f

// ---------------------------------------------------------------------------
// 128x128 fp32 GEMM body: C[M,N] = A[M,K] @ W[K,N] + bias (+ residual).
// 256 threads, 8x8 per thread as 2x2 sub-blocks of 4 consecutive elements
// -> all LDS compute reads are ds_read_b128. A staged k-major (transposed).
// M,N,K % 128 == 0.
// ---------------------------------------------------------------------------
__device__ __forceinline__ void gemm128_body(
    const float* __restrict__ A, const float* __restrict__ W,
    const float* __restrict__ bias, const float* __restrict__ residual,
    float* __restrict__ C, int M, int N, int K, int bx, int by)
{
    __shared__ float As[16][132];   // [k][row], pad 132 (2-way max on writes)
    __shared__ float Ws[16][132];   // [k][col]

    const int tid = threadIdx.x;
    const int tx = tid & 15, ty = tid >> 4;
    const int row0 = by * 128, col0 = bx * 128;

    float c[8][8];
#pragma unroll
    for (int i = 0; i < 8; ++i)
#pragma unroll
        for (int j = 0; j < 8; ++j) c[i][j] = 0.f;

    for (int k0 = 0; k0 < K; k0 += 16) {
        // Stage A: 128 rows x 16 k. Thread loads 2 float4 along K, writes
        // transposed (scalar, <=2-way bank alias with pad 132).
#pragma unroll
        for (int l = 0; l < 2; ++l) {
            int idx = tid + l * 256;            // 0..511
            int r = idx >> 2;                   // 0..127
            int k4 = (idx & 3) * 4;             // 0,4,8,12
            const float4 a = *(const float4*)&A[(size_t)(row0 + r) * K + k0 + k4];
            As[k4 + 0][r] = a.x; As[k4 + 1][r] = a.y;
            As[k4 + 2][r] = a.z; As[k4 + 3][r] = a.w;
        }
        // Stage W: 16 k x 128 cols, float4 in/out (coalesced).
#pragma unroll
        for (int l = 0; l < 2; ++l) {
            int idx = tid + l * 256;
            int kk = idx >> 5;                  // 0..15
            int cc = (idx & 31) * 4;            // 0..124
            *(float4*)&Ws[kk][cc] =
                *(const float4*)&W[(size_t)(k0 + kk) * N + col0 + cc];
        }
        __syncthreads();
#pragma unroll
        for (int kk = 0; kk < 16; ++kk) {
            const float4 a0 = *(const float4*)&As[kk][ty * 4];
            const float4 a1 = *(const float4*)&As[kk][64 + ty * 4];
            const float4 w0 = *(const float4*)&Ws[kk][tx * 4];
            const float4 w1 = *(const float4*)&Ws[kk][64 + tx * 4];
            const float av[8] = {a0.x, a0.y, a0.z, a0.w, a1.x, a1.y, a1.z, a1.w};
            const float wv[8] = {w0.x, w0.y, w0.z, w0.w, w1.x, w1.y, w1.z, w1.w};
#pragma unroll
            for (int i = 0; i < 8; ++i)
#pragma unroll
                for (int j = 0; j < 8; ++j)
                    c[i][j] = fmaf(av[i], wv[j], c[i][j]);
        }
        __syncthreads();
    }

#pragma unroll
    for (int ih = 0; ih < 2; ++ih) {
#pragma unroll
        for (int i = 0; i < 4; ++i) {
            int r = row0 + ih * 64 + ty * 4 + i;
#pragma unroll
            for (int jh = 0; jh < 2; ++jh) {
                int cc = col0 + jh * 64 + tx * 4;
                const float4 b4 = *(const float4*)&bias[cc];
                float4 o;
                o.x = c[ih * 4 + i][jh * 4 + 0] + b4.x;
                o.y = c[ih * 4 + i][jh * 4 + 1] + b4.y;
                o.z = c[ih * 4 + i][jh * 4 + 2] + b4.z;
                o.w = c[ih * 4 + i][jh * 4 + 3] + b4.w;
                if (residual) {
                    const float4 rr = *(const float4*)&residual[(size_t)r * N + cc];
                    o.x += rr.x; o.y += rr.y; o.z += rr.z; o.w += rr.w;
                }
                *(float4*)&C[(size_t)r * N + cc] = o;
            }
        }
    }
}

// Batched QKV projection: z in {0,1,2} selects (A, W, bias, C).
__global__ __launch_bounds__(256) void gemm_qkv_kernel(
    const float* __restrict__ q, const float* __restrict__ k,
    const float* __restrict__ v,
    const float* __restrict__ wq, const float* __restrict__ wk,
    const float* __restrict__ wv,
    const float* __restrict__ bq, const float* __restrict__ bk,
    const float* __restrict__ bv,
    float* __restrict__ Qf, float* __restrict__ Kf, float* __restrict__ Vf)
{
    const int z = blockIdx.z;
    const float* A    = (z == 0) ? q  : (z == 1) ? k  : v;
    const float* W    = (z == 0) ? wq : (z == 1) ? wk : wv;
    const float* bias = (z == 0) ? bq : (z == 1) ? bk : bv;
    float*       C    = (z == 0) ? Qf : (z == 1) ? Kf : Vf;
    gemm128_body(A, W, bias, nullptr, C, B_ * S_, D_, D_,
                 blockIdx.x, blockIdx.y);
}

// Plain GEMM (+bias, +residual) for the output projection.
__global__ __launch_bounds__(256) void gemm128_kernel(
    const float* __restrict__ A, const float* __restrict__ W,
    const float* __restrict__ bias, const float* __restrict__ residual,
    float* __restrict__ C, int M, int N, int K)
{
    gemm128_body(A, W, bias, residual, C, M, N, K, blockIdx.x, blockIdx.y);
}

// ---------------------------------------------------------------------------
// QK^T: logits[bh, q, k] = 0.125 * sum_d Q[b,q,h*64+d] * K[b,k,h*64+d]
// One block per lower-triangular 64x64 tile per (b,h). Upper tiles skipped.
// Both tiles staged k-major; compute reads are ds_read_b128.
// ---------------------------------------------------------------------------
__global__ __launch_bounds__(256) void qk_kernel(
    const float* __restrict__ Q, const float* __restrict__ Km,
    float* __restrict__ logits)
{
    const int tk = blockIdx.x, tq = blockIdx.y;
    if (tk > tq) return;
    const int bh = blockIdx.z;
    const int b = bh >> 4, h = bh & 15;
    const int tid = threadIdx.x;
    const int tx = tid & 15, ty = tid >> 4;

    __shared__ float Qs[16][68];   // [d][q-row]
    __shared__ float Ks[16][68];   // [d][k-row]

    const size_t base = ((size_t)b * S_) * D_ + (size_t)h * DH_;
    const float* Aq = Q  + base + (size_t)(tq * 64) * D_;
    const float* Ak = Km + base + (size_t)(tk * 64) * D_;

    float c[4][4];
#pragma unroll
    for (int i = 0; i < 4; ++i)
#pragma unroll
        for (int j = 0; j < 4; ++j) c[i][j] = 0.f;

    for (int d0 = 0; d0 < DH_; d0 += 16) {
        {
            int r = tid >> 2, k4 = (tid & 3) * 4;
            const float4 qv = *(const float4*)&Aq[(size_t)r * D_ + d0 + k4];
            Qs[k4 + 0][r] = qv.x; Qs[k4 + 1][r] = qv.y;
            Qs[k4 + 2][r] = qv.z; Qs[k4 + 3][r] = qv.w;
            const float4 kv = *(const float4*)&Ak[(size_t)r * D_ + d0 + k4];
            Ks[k4 + 0][r] = kv.x; Ks[k4 + 1][r] = kv.y;
            Ks[k4 + 2][r] = kv.z; Ks[k4 + 3][r] = kv.w;
        }
        __syncthreads();
#pragma unroll
        for (int kk = 0; kk < 16; ++kk) {
            const float4 a = *(const float4*)&Qs[kk][ty * 4];
            const float4 w = *(const float4*)&Ks[kk][tx * 4];
            const float av[4] = {a.x, a.y, a.z, a.w};
            const float wv[4] = {w.x, w.y, w.z, w.w};
#pragma unroll
            for (int i = 0; i < 4; ++i)
#pragma unroll
                for (int j = 0; j < 4; ++j)
                    c[i][j] = fmaf(av[i], wv[j], c[i][j]);
        }
        __syncthreads();
    }

    float* orow = logits + ((size_t)bh * S_ + (size_t)(tq * 64)) * S_ + tk * 64;
#pragma unroll
    for (int i = 0; i < 4; ++i) {
        float4 o;
        o.x = c[i][0] * 0.125f; o.y = c[i][1] * 0.125f;
        o.z = c[i][2] * 0.125f; o.w = c[i][3] * 0.125f;
        *(float4*)&orow[(size_t)(ty * 4 + i) * S_ + tx * 4] = o;
    }
}

// ---------------------------------------------------------------------------
// Row softmax over logits, in place. One block per (q-row, bh).
// float4 global reads with -INF masking of >=len lanes (poison-safe);
// causal tail written as exact 0 (matches exp(-1e4 - m) fp32 underflow).
// ---------------------------------------------------------------------------
__global__ __launch_bounds__(256) void softmax_kernel(float* __restrict__ attn)
{
    const int qi = blockIdx.x;
    const int bh = blockIdx.y;
    const int tid = threadIdx.x;
    const int lane = tid & 63, wid = tid >> 6;
    float* row = attn + ((size_t)bh * S_ + qi) * S_;
    const int len = qi + 1;
    const int len4 = (len + 3) >> 2;

    __shared__ float lg[S_];
    __shared__ float red[8];

    const float4* row4 = (const float4*)row;
    float lmax = -INFINITY;
    for (int j4 = tid; j4 < len4; j4 += 256) {
        float4 v = row4[j4];
        const int j = j4 * 4;
        if (j + 1 >= len) v.y = -INFINITY;   // mask beyond-len lanes (garbage)
        if (j + 2 >= len) v.z = -INFINITY;
        if (j + 3 >= len) v.w = -INFINITY;
        *(float4*)&lg[j] = v;
        lmax = fmaxf(fmaxf(lmax, fmaxf(v.x, v.y)), fmaxf(v.z, v.w));
    }
#pragma unroll
    for (int o = 32; o > 0; o >>= 1) lmax = fmaxf(lmax, __shfl_xor(lmax, o));
    if (lane == 0) red[wid] = lmax;
    __syncthreads();
    const float m = fmaxf(fmaxf(red[0], red[1]), fmaxf(red[2], red[3]));

    float lsum = 0.f;
    for (int j = tid; j < len; j += 256) {
        float e = __expf(lg[j] - m);
        lg[j] = e;
        lsum += e;
    }
#pragma unroll
    for (int o = 32; o > 0; o >>= 1) lsum += __shfl_xor(lsum, o);
    if (lane == 0) red[4 + wid] = lsum;
    __syncthreads();
    const float inv = 1.f / (red[4] + red[5] + red[6] + red[7]);

    float4* wrow4 = (float4*)row;
    for (int j4 = tid; j4 < S_ / 4; j4 += 256) {
        const int j = j4 * 4;
        float4 o;
        o.x = (j     < len) ? lg[j]     * inv : 0.f;
        o.y = (j + 1 < len) ? lg[j + 1] * inv : 0.f;
        o.z = (j + 2 < len) ? lg[j + 2] * inv : 0.f;
        o.w = (j + 3 < len) ? lg[j + 3] * inv : 0.f;
        wrow4[j4] = o;
    }
}

// ---------------------------------------------------------------------------
// PV split-K: ctx[b,q,h*64+d] += sum_{k in span} attn[bh,q,k] * V[b,k,h*64+d]
// Grid (tq, bh, split); each active block covers a 256-key span -> balanced.
// Partials accumulated via fp32 atomicAdd into zeroed ctx.
// ---------------------------------------------------------------------------
__global__ __launch_bounds__(256) void pv_kernel(
    const float* __restrict__ P, const float* __restrict__ V,
    float* __restrict__ ctx)
{
    const int tq = blockIdx.x;
    const int bh = blockIdx.y;
    const int sp = blockIdx.z;
    const int Kext = (tq + 1) * 64;
    const int kb = sp * 256;
    if (kb >= Kext) return;
    const int ke = (kb + 256 < Kext) ? kb + 256 : Kext;

    const int b = bh >> 4, h = bh & 15;
    const int tid = threadIdx.x;
    const int tx = tid & 15, ty = tid >> 4;

    __shared__ float As[16][68];   // [k][q-row] (attn tile, transposed)
    __shared__ float Ws[16][68];   // [k][d]     (V tile)

    const float* A = P + ((size_t)bh * S_ + (size_t)(tq * 64)) * S_; // stride S
    const float* W = V + ((size_t)b * S_) * D_ + h * DH_;            // stride D

    float c[4][4];
#pragma unroll
    for (int i = 0; i < 4; ++i)
#pragma unroll
        for (int j = 0; j < 4; ++j) c[i][j] = 0.f;

    for (int k0 = kb; k0 < ke; k0 += 16) {
        {
            int r = tid >> 2, k4 = (tid & 3) * 4;
            const float4 av = *(const float4*)&A[(size_t)r * S_ + k0 + k4];
            As[k4 + 0][r] = av.x; As[k4 + 1][r] = av.y;
            As[k4 + 2][r] = av.z; As[k4 + 3][r] = av.w;
            int kk = tid >> 4, cc = (tid & 15) * 4;
            *(float4*)&Ws[kk][cc] =
                *(const float4*)&W[(size_t)(k0 + kk) * D_ + cc];
        }
        __syncthreads();
#pragma unroll
        for (int kk = 0; kk < 16; ++kk) {
            const float4 a = *(const float4*)&As[kk][ty * 4];
            const float4 w = *(const float4*)&Ws[kk][tx * 4];
            const float av[4] = {a.x, a.y, a.z, a.w};
            const float wv[4] = {w.x, w.y, w.z, w.w};
#pragma unroll
            for (int i = 0; i < 4; ++i)
#pragma unroll
                for (int j = 0; j < 4; ++j)
                    c[i][j] = fmaf(av[i], wv[j], c[i][j]);
        }
        __syncthreads();
    }

    float* C = ctx + ((size_t)b * S_ + (size_t)(tq * 64)) * D_ + h * DH_;
#pragma unroll
    for (int i = 0; i < 4; ++i) {
        const int r = ty * 4 + i;
#pragma unroll
        for (int j = 0; j < 4; ++j)
            atomicAdd(&C[(size_t)r * D_ + tx * 4 + j], c[i][j]);
    }
}

// ---------------------------------------------------------------------------
// Row LayerNorm: one block per row of [B*S, D], fp32 in, fp32 out.
// ---------------------------------------------------------------------------
__global__ __launch_bounds__(256) void ln_kernel(
    const float* __restrict__ X, const float* __restrict__ gamma,
    const float* __restrict__ beta, float* __restrict__ out)
{
    const int row = blockIdx.x;
    const int tid = threadIdx.x;
    const float* x = X + (size_t)row * D_;
    __shared__ float red[256];

    float s = 0.f;
    for (int i = tid; i < D_; i += 256) s += x[i];
    red[tid] = s;
    __syncthreads();
    for (int t = 128; t > 0; t >>= 1) {
        if (tid < t) red[tid] += red[tid + t];
        __syncthreads();
    }
    const float mu = red[0] * (1.f / D_);
    __syncthreads();

    float v = 0.f;
    for (int i = tid; i < D_; i += 256) {
        float t = x[i] - mu;
        v += t * t;
    }
    red[tid] = v;
    __syncthreads();
    for (int t = 128; t > 0; t >>= 1) {
        if (tid < t) red[tid] += red[tid + t];
        __syncthreads();
    }
    const float r = rsqrtf(red[0] * (1.f / D_) + EPS_);

    for (int i = tid; i < D_; i += 256) {
        float o = (x[i] - mu) * r * gamma[i] + beta[i];
        out[(size_t)row * D_ + i] = o;
    }
}

// ---------------------------------------------------------------------------
extern "C" void kernel_launch(void* const* d_in, const int* in_sizes, int n_in,
                              void* d_out, int out_size, void* d_ws, size_t ws_size,
                              hipStream_t stream)
{
    const float* query = (const float*)d_in[0];
    const float* key   = (const float*)d_in[1];
    const float* value = (const float*)d_in[2];
    // d_in[3] = mask (causal) — applied structurally (lower-tri tiles + zero tail)
    const float* wq_w = (const float*)d_in[4];
    const float* wq_b = (const float*)d_in[5];
    const float* wk_w = (const float*)d_in[6];
    const float* wk_b = (const float*)d_in[7];
    const float* wv_w = (const float*)d_in[8];
    const float* wv_b = (const float*)d_in[9];
    const float* wo_w = (const float*)d_in[10];
    const float* wo_b = (const float*)d_in[11];
    const float* ln_g = (const float*)d_in[12];
    const float* ln_b = (const float*)d_in[13];

    float* out_f  = (float*)d_out;                        // (B,S,D)
    float* attn_f = out_f + (size_t)B_ * S_ * D_;         // (B,H,S,S) — also the
                                                          // logits scratch (in-place)

    const size_t MAT = (size_t)B_ * S_ * D_;  // 4,194,304 floats (16 MB)
    float* ws  = (float*)d_ws;
    float* Qf  = ws;            // dead after qk; reused for pre-LN
    float* Kf  = ws + MAT;
    float* Vf  = ws + 2 * MAT;
    float* ctx = ws + 3 * MAT;
    float* pre = Qf;            // alias: pre-LN buffer

    const int M = B_ * S_, N = D_, K = D_;

    // Fused QKV projections (z = 0,1,2): 768 blocks.
    hipLaunchKernelGGL(gemm_qkv_kernel, dim3(N / 128, M / 128, 3), dim3(256),
                       0, stream,
                       query, key, value, wq_w, wk_w, wv_w, wq_b, wk_b, wv_b,
                       Qf, Kf, Vf);

    // Zero ctx for pv's atomic accumulation (stream-ordered, capture-safe).
    hipMemsetAsync(ctx, 0, MAT * sizeof(float), stream);

    // QK^T (lower-tri 64x64 tiles) -> logits in attn buffer
    hipLaunchKernelGGL(qk_kernel, dim3(S_ / 64, S_ / 64, B_ * H_), dim3(256),
                       0, stream, Qf, Kf, attn_f);

    // Row softmax in place (writes normalized probs + zero causal tail)
    hipLaunchKernelGGL(softmax_kernel, dim3(S_, B_ * H_), dim3(256), 0, stream,
                       attn_f);

    // PV split-K -> ctx (B,S,D), balanced 256-key spans + atomic accumulate
    hipLaunchKernelGGL(pv_kernel, dim3(S_ / 64, B_ * H_, S_ / 256), dim3(256),
                       0, stream, attn_f, Vf, ctx);

    // Output projection + residual, then LayerNorm
    hipLaunchKernelGGL(gemm128_kernel, dim3(N / 128, M / 128), dim3(256),
                       0, stream, ctx, wo_w, wo_b, query, pre, M, N, K);

    hipLaunchKernelGGL(ln_kernel, dim3(B_ * S_), dim3(256), 0, stream,
                       pre, ln_g, ln_b, out_f);
}

// Round 3
// 1224.983 us; speedup vs baseline: 3.6334x; 1.2841x over previous
//
#include <hip/hip_runtime.h>

// Problem constants (MultiHeadAttention_14508399526473)
// Inputs fp32 (per reference). Outputs fp32: [out (B,S,D) | attn (B,H,S,S)].
#define B_ 2
#define S_ 2048
#define D_ 1024
#define H_ 16
#define DH_ 64
#define EPS_ 1e-6f

typedef short bf16x8 __attribute__((ext_vector_type(8)));  // 8 bf16 (4 VGPRs)
typedef float f32x4  __attribute__((ext_vector_type(4)));  // MFMA accumulator

// --- bf16 split helpers (RNE). x = hi + lo captures ~16 mantissa bits. ---
__device__ __forceinline__ ushort f2bf(float x) {
    uint u = __float_as_uint(x);
    return (ushort)((u + 0x7fffu + ((u >> 16) & 1u)) >> 16);
}
__device__ __forceinline__ float bf2f(ushort h) {
    return __uint_as_float(((uint)h) << 16);
}
__device__ __forceinline__ void split_bf(float x, ushort& hi, ushort& lo) {
    hi = f2bf(x);
    lo = f2bf(x - bf2f(hi));   // x - hi exact in fp32 (nearby values)
}

// ---------------------------------------------------------------------------
// Weight prep: W[k][n] fp32 -> Wt_hi/Wt_lo[n][k] bf16 (k-contiguous), 4 mats.
// ---------------------------------------------------------------------------
__global__ __launch_bounds__(256) void prep_weights_kernel(
    const float* __restrict__ w0, const float* __restrict__ w1,
    const float* __restrict__ w2, const float* __restrict__ w3,
    ushort* __restrict__ Wth, ushort* __restrict__ Wtl)
{
    const int wi = blockIdx.z;
    const float* W = (wi == 0) ? w0 : (wi == 1) ? w1 : (wi == 2) ? w2 : w3;
    ushort* th = Wth + (size_t)wi * D_ * D_;
    ushort* tl = Wtl + (size_t)wi * D_ * D_;
    const int k0 = blockIdx.x * 32, n0 = blockIdx.y * 32;
    const int tid = threadIdx.x;
    __shared__ float t[32][33];
#pragma unroll
    for (int l = 0; l < 4; ++l) {
        int idx = tid + l * 256;
        int kk = idx >> 5, nn = idx & 31;
        t[kk][nn] = W[(size_t)(k0 + kk) * D_ + n0 + nn];
    }
    __syncthreads();
#pragma unroll
    for (int l = 0; l < 4; ++l) {
        int idx = tid + l * 256;
        int nn = idx >> 5, kk = idx & 31;
        ushort h, lo;
        split_bf(t[kk][nn], h, lo);
        th[(size_t)(n0 + nn) * D_ + k0 + kk] = h;
        tl[(size_t)(n0 + nn) * D_ + k0 + kk] = lo;
    }
}

// ---------------------------------------------------------------------------
// Split-bf16 MFMA GEMM body: C[M,N] = A[M,K] @ B[K,N] (+bias, +residual)
// A fp32, staged+split to LDS. B pre-split bf16 as Bt[n][k] (direct global).
// Block 128x128, 4 waves, each 64x64 = 4x4 frags of 16x16x32.
// MODE 0: fp32 out (+bias,+residual). MODE 1: bf16 hi/lo out [M][N].
// MODE 2: bf16 hi/lo out transposed per head: [b][h][dh][S].
// ---------------------------------------------------------------------------
template <int MODE>
__device__ __forceinline__ void gemm_mfma_body(
    const float* __restrict__ A, const ushort* __restrict__ Bh,
    const ushort* __restrict__ Bl, const float* __restrict__ bias,
    const float* __restrict__ residual, float* __restrict__ Cf,
    ushort* __restrict__ Ch, ushort* __restrict__ Cl,
    int M, int N, int K, int bx, int by)
{
    __shared__ ushort Ah[128][40];   // [m][k], pad 40 shorts (80 B rows)
    __shared__ ushort Al[128][40];

    const int tid = threadIdx.x;
    const int lane = tid & 63, w = tid >> 6;
    const int l15 = lane & 15, l4 = lane >> 4;
    const int row0 = by * 128, col0 = bx * 128;
    const int wm = (w >> 1) * 64, wn = (w & 1) * 64;

    const f32x4 zf = {0.f, 0.f, 0.f, 0.f};
    f32x4 acc[4][4];
#pragma unroll
    for (int i = 0; i < 4; ++i)
#pragma unroll
        for (int j = 0; j < 4; ++j) acc[i][j] = zf;

    for (int k0 = 0; k0 < K; k0 += 32) {
        // Stage A: 128 rows x 32 k fp32 -> hi/lo bf16 LDS.
#pragma unroll
        for (int l = 0; l < 4; ++l) {
            int idx = tid + l * 256;            // 0..1023
            int r = idx >> 3, c4 = (idx & 7) * 4;
            const float4 a = *(const float4*)&A[(size_t)(row0 + r) * K + k0 + c4];
            ushort h0, h1, h2, h3, q0, q1, q2, q3;
            split_bf(a.x, h0, q0); split_bf(a.y, h1, q1);
            split_bf(a.z, h2, q2); split_bf(a.w, h3, q3);
            *(ushort4*)&Ah[r][c4] = make_ushort4(h0, h1, h2, h3);
            *(ushort4*)&Al[r][c4] = make_ushort4(q0, q1, q2, q3);
        }
        // B fragments (global, L2-hot) issued before the barrier.
        bf16x8 bh_[4], bl_[4];
#pragma unroll
        for (int j = 0; j < 4; ++j) {
            const size_t bo = (size_t)(col0 + wn + j * 16 + l15) * K + k0 + l4 * 8;
            bh_[j] = *(const bf16x8*)&Bh[bo];
            bl_[j] = *(const bf16x8*)&Bl[bo];
        }
        __syncthreads();
        bf16x8 ah_[4], al_[4];
#pragma unroll
        for (int i = 0; i < 4; ++i) {
            ah_[i] = *(const bf16x8*)&Ah[wm + i * 16 + l15][l4 * 8];
            al_[i] = *(const bf16x8*)&Al[wm + i * 16 + l15][l4 * 8];
        }
#pragma unroll
        for (int i = 0; i < 4; ++i)
#pragma unroll
            for (int j = 0; j < 4; ++j) {
                acc[i][j] = __builtin_amdgcn_mfma_f32_16x16x32_bf16(
                    ah_[i], bh_[j], acc[i][j], 0, 0, 0);
                acc[i][j] = __builtin_amdgcn_mfma_f32_16x16x32_bf16(
                    ah_[i], bl_[j], acc[i][j], 0, 0, 0);
                acc[i][j] = __builtin_amdgcn_mfma_f32_16x16x32_bf16(
                    al_[i], bh_[j], acc[i][j], 0, 0, 0);
            }
        __syncthreads();
    }

    // Epilogue. D frag: col = l15, row = l4*4 + e (m89-verified layout).
#pragma unroll
    for (int i = 0; i < 4; ++i) {
#pragma unroll
        for (int j = 0; j < 4; ++j) {
            const int col = col0 + wn + j * 16 + l15;
            const float bb = bias[col];
            const int mbase = row0 + wm + i * 16 + l4 * 4;
            if (MODE == 0) {
#pragma unroll
                for (int e = 0; e < 4; ++e) {
                    const int m = mbase + e;
                    float v = acc[i][j][e] + bb;
                    if (residual) v += residual[(size_t)m * N + col];
                    Cf[(size_t)m * N + col] = v;
                }
            } else if (MODE == 1) {
#pragma unroll
                for (int e = 0; e < 4; ++e) {
                    const int m = mbase + e;
                    ushort h, lo;
                    split_bf(acc[i][j][e] + bb, h, lo);
                    Ch[(size_t)m * N + col] = h;
                    Cl[(size_t)m * N + col] = lo;
                }
            } else {
                // Vt: [b][h][dh][S]; 4 consecutive s -> one ushort4 store.
                const int bb_ = mbase / S_;
                const int s0 = mbase - bb_ * S_;
                const int hh = col >> 6, dh = col & 63;
                ushort hv[4], lv[4];
#pragma unroll
                for (int e = 0; e < 4; ++e)
                    split_bf(acc[i][j][e] + bb, hv[e], lv[e]);
                const size_t ofs =
                    (((size_t)bb_ * H_ + hh) * DH_ + dh) * S_ + s0;
                *(ushort4*)&Ch[ofs] = make_ushort4(hv[0], hv[1], hv[2], hv[3]);
                *(ushort4*)&Cl[ofs] = make_ushort4(lv[0], lv[1], lv[2], lv[3]);
            }
        }
    }
}

// Fused QKV projections: z=0 -> Q bf16, z=1 -> K bf16, z=2 -> V transposed.
__global__ __launch_bounds__(256) void gemm_qkv_mfma(
    const float* __restrict__ q, const float* __restrict__ k,
    const float* __restrict__ v,
    const ushort* __restrict__ Wth, const ushort* __restrict__ Wtl,
    const float* __restrict__ bq, const float* __restrict__ bk,
    const float* __restrict__ bv,
    ushort* __restrict__ Qh, ushort* __restrict__ Ql,
    ushort* __restrict__ Kh, ushort* __restrict__ Kl,
    ushort* __restrict__ Vth, ushort* __restrict__ Vtl)
{
    const int z = blockIdx.z;
    const size_t wofs = (size_t)z * D_ * D_;
    if (z == 0)
        gemm_mfma_body<1>(q, Wth, Wtl, bq, nullptr, nullptr, Qh, Ql,
                          B_ * S_, D_, D_, blockIdx.x, blockIdx.y);
    else if (z == 1)
        gemm_mfma_body<1>(k, Wth + wofs, Wtl + wofs, bk, nullptr, nullptr,
                          Kh, Kl, B_ * S_, D_, D_, blockIdx.x, blockIdx.y);
    else
        gemm_mfma_body<2>(v, Wth + wofs, Wtl + wofs, bv, nullptr, nullptr,
                          Vth, Vtl, B_ * S_, D_, D_, blockIdx.x, blockIdx.y);
}

// Output projection: pre = ctx @ wo + bias + residual(query).
__global__ __launch_bounds__(256) void gemm_out_mfma(
    const float* __restrict__ ctx, const ushort* __restrict__ Wth,
    const ushort* __restrict__ Wtl, const float* __restrict__ bias,
    const float* __restrict__ residual, float* __restrict__ pre)
{
    gemm_mfma_body<0>(ctx, Wth, Wtl, bias, residual, pre, nullptr, nullptr,
                      B_ * S_, D_, D_, blockIdx.x, blockIdx.y);
}

// ---------------------------------------------------------------------------
// QK^T: logits = 0.125 * Q @ K^T per (b,h); lower-tri 128x128 tiles.
// LDS-free: A/B fragments load straight from bf16 Q/K (L2-hot). K=64.
// ---------------------------------------------------------------------------
__global__ __launch_bounds__(256) void qk_mfma_kernel(
    const ushort* __restrict__ Qh, const ushort* __restrict__ Ql,
    const ushort* __restrict__ Kh, const ushort* __restrict__ Kl,
    float* __restrict__ logits)
{
    const int tk = blockIdx.x, tq = blockIdx.y;
    if (tk > tq) return;
    const int bh = blockIdx.z, b = bh >> 4, h = bh & 15;
    const int tid = threadIdx.x;
    const int lane = tid & 63, w = tid >> 6;
    const int l15 = lane & 15, l4 = lane >> 4;
    const int wm = (w >> 1) * 64, wn = (w & 1) * 64;

    const size_t qbase = ((size_t)b * S_ + tq * 128 + wm) * D_ + h * DH_;
    const size_t kbase = ((size_t)b * S_ + tk * 128 + wn) * D_ + h * DH_;

    const f32x4 zf = {0.f, 0.f, 0.f, 0.f};
    f32x4 acc[4][4];
#pragma unroll
    for (int i = 0; i < 4; ++i)
#pragma unroll
        for (int j = 0; j < 4; ++j) acc[i][j] = zf;

#pragma unroll
    for (int ks = 0; ks < 2; ++ks) {
        const int ko = ks * 32 + l4 * 8;
        bf16x8 ah_[4], al_[4], bh_[4], bl_[4];
#pragma unroll
        for (int i = 0; i < 4; ++i) {
            const size_t qo = qbase + (size_t)(i * 16 + l15) * D_ + ko;
            ah_[i] = *(const bf16x8*)&Qh[qo];
            al_[i] = *(const bf16x8*)&Ql[qo];
            const size_t kko = kbase + (size_t)(i * 16 + l15) * D_ + ko;
            bh_[i] = *(const bf16x8*)&Kh[kko];
            bl_[i] = *(const bf16x8*)&Kl[kko];
        }
#pragma unroll
        for (int i = 0; i < 4; ++i)
#pragma unroll
            for (int j = 0; j < 4; ++j) {
                acc[i][j] = __builtin_amdgcn_mfma_f32_16x16x32_bf16(
                    ah_[i], bh_[j], acc[i][j], 0, 0, 0);
                acc[i][j] = __builtin_amdgcn_mfma_f32_16x16x32_bf16(
                    ah_[i], bl_[j], acc[i][j], 0, 0, 0);
                acc[i][j] = __builtin_amdgcn_mfma_f32_16x16x32_bf16(
                    al_[i], bh_[j], acc[i][j], 0, 0, 0);
            }
    }

    float* out = logits + ((size_t)bh * S_ + tq * 128 + wm) * S_ + tk * 128 + wn;
#pragma unroll
    for (int i = 0; i < 4; ++i)
#pragma unroll
        for (int j = 0; j < 4; ++j) {
            const int col = j * 16 + l15;
#pragma unroll
            for (int e = 0; e < 4; ++e) {
                const int m = i * 16 + l4 * 4 + e;
                out[(size_t)m * S_ + col] = acc[i][j][e] * 0.125f;
            }
        }
}

// ---------------------------------------------------------------------------
// Row softmax over logits, in place. One block per (q-row, bh). (verified)
// ---------------------------------------------------------------------------
__global__ __launch_bounds__(256) void softmax_kernel(float* __restrict__ attn)
{
    const int qi = blockIdx.x;
    const int bh = blockIdx.y;
    const int tid = threadIdx.x;
    const int lane = tid & 63, wid = tid >> 6;
    float* row = attn + ((size_t)bh * S_ + qi) * S_;
    const int len = qi + 1;
    const int len4 = (len + 3) >> 2;

    __shared__ float lg[S_];
    __shared__ float red[8];

    const float4* row4 = (const float4*)row;
    float lmax = -INFINITY;
    for (int j4 = tid; j4 < len4; j4 += 256) {
        float4 v = row4[j4];
        const int j = j4 * 4;
        if (j + 1 >= len) v.y = -INFINITY;
        if (j + 2 >= len) v.z = -INFINITY;
        if (j + 3 >= len) v.w = -INFINITY;
        *(float4*)&lg[j] = v;
        lmax = fmaxf(fmaxf(lmax, fmaxf(v.x, v.y)), fmaxf(v.z, v.w));
    }
#pragma unroll
    for (int o = 32; o > 0; o >>= 1) lmax = fmaxf(lmax, __shfl_xor(lmax, o));
    if (lane == 0) red[wid] = lmax;
    __syncthreads();
    const float m = fmaxf(fmaxf(red[0], red[1]), fmaxf(red[2], red[3]));

    float lsum = 0.f;
    for (int j = tid; j < len; j += 256) {
        float e = __expf(lg[j] - m);
        lg[j] = e;
        lsum += e;
    }
#pragma unroll
    for (int o = 32; o > 0; o >>= 1) lsum += __shfl_xor(lsum, o);
    if (lane == 0) red[4 + wid] = lsum;
    __syncthreads();
    const float inv = 1.f / (red[4] + red[5] + red[6] + red[7]);

    float4* wrow4 = (float4*)row;
    for (int j4 = tid; j4 < S_ / 4; j4 += 256) {
        const int j = j4 * 4;
        float4 o;
        o.x = (j     < len) ? lg[j]     * inv : 0.f;
        o.y = (j + 1 < len) ? lg[j + 1] * inv : 0.f;
        o.z = (j + 2 < len) ? lg[j + 2] * inv : 0.f;
        o.w = (j + 3 < len) ? lg[j + 3] * inv : 0.f;
        wrow4[j4] = o;
    }
}

// ---------------------------------------------------------------------------
// PV: ctx += attn @ V per (b,h). 256-q-row tiles, split-K (256-key spans),
// fp32 atomics into zeroed ctx. attn split on the fly; Vt direct from L2.
// ---------------------------------------------------------------------------
__global__ __launch_bounds__(256) void pv_mfma_kernel(
    const float* __restrict__ P, const ushort* __restrict__ Vth,
    const ushort* __restrict__ Vtl, float* __restrict__ ctx)
{
    const int tq = blockIdx.x, bh = blockIdx.y, sp = blockIdx.z;
    if (sp > tq) return;                    // keys beyond diagonal: attn == 0
    const int b = bh >> 4, h = bh & 15;
    const int tid = threadIdx.x;
    const int lane = tid & 63, w = tid >> 6;
    const int l15 = lane & 15, l4 = lane >> 4;
    const int wm = w * 64;                  // wave: 64 q-rows x 64 dh

    __shared__ ushort Ph[256][40];
    __shared__ ushort Pl[256][40];

    const float* Arow = P + ((size_t)bh * S_ + (size_t)tq * 256) * S_;
    const size_t vbase = ((size_t)b * H_ + h) * (size_t)DH_ * S_;

    const f32x4 zf = {0.f, 0.f, 0.f, 0.f};
    f32x4 acc[4][4];
#pragma unroll
    for (int i = 0; i < 4; ++i)
#pragma unroll
        for (int j = 0; j < 4; ++j) acc[i][j] = zf;

    const int kb = sp * 256;
    for (int k0 = kb; k0 < kb + 256; k0 += 32) {
#pragma unroll
        for (int l = 0; l < 8; ++l) {
            int idx = tid + l * 256;        // 0..2047
            int r = idx >> 3, c4 = (idx & 7) * 4;
            const float4 a = *(const float4*)&Arow[(size_t)r * S_ + k0 + c4];
            ushort h0, h1, h2, h3, q0, q1, q2, q3;
            split_bf(a.x, h0, q0); split_bf(a.y, h1, q1);
            split_bf(a.z, h2, q2); split_bf(a.w, h3, q3);
            *(ushort4*)&Ph[r][c4] = make_ushort4(h0, h1, h2, h3);
            *(ushort4*)&Pl[r][c4] = make_ushort4(q0, q1, q2, q3);
        }
        bf16x8 bh_[4], bl_[4];
#pragma unroll
        for (int j = 0; j < 4; ++j) {
            const size_t vo = vbase + (size_t)(j * 16 + l15) * S_ + k0 + l4 * 8;
            bh_[j] = *(const bf16x8*)&Vth[vo];
            bl_[j] = *(const bf16x8*)&Vtl[vo];
        }
        __syncthreads();
        bf16x8 ah_[4], al_[4];
#pragma unroll
        for (int i = 0; i < 4; ++i) {
            ah_[i] = *(const bf16x8*)&Ph[wm + i * 16 + l15][l4 * 8];
            al_[i] = *(const bf16x8*)&Pl[wm + i * 16 + l15][l4 * 8];
        }
#pragma unroll
        for (int i = 0; i < 4; ++i)
#pragma unroll
            for (int j = 0; j < 4; ++j) {
                acc[i][j] = __builtin_amdgcn_mfma_f32_16x16x32_bf16(
                    ah_[i], bh_[j], acc[i][j], 0, 0, 0);
                acc[i][j] = __builtin_amdgcn_mfma_f32_16x16x32_bf16(
                    ah_[i], bl_[j], acc[i][j], 0, 0, 0);
                acc[i][j] = __builtin_amdgcn_mfma_f32_16x16x32_bf16(
                    al_[i], bh_[j], acc[i][j], 0, 0, 0);
            }
        __syncthreads();
    }

    float* C = ctx + ((size_t)b * S_ + (size_t)tq * 256 + wm) * D_ + h * DH_;
#pragma unroll
    for (int i = 0; i < 4; ++i)
#pragma unroll
        for (int j = 0; j < 4; ++j) {
            const int col = j * 16 + l15;
#pragma unroll
            for (int e = 0; e < 4; ++e) {
                const int m = i * 16 + l4 * 4 + e;
                atomicAdd(&C[(size_t)m * D_ + col], acc[i][j][e]);
            }
        }
}

// ---------------------------------------------------------------------------
// Row LayerNorm: one block per row of [B*S, D], fp32 in, fp32 out. (verified)
// ---------------------------------------------------------------------------
__global__ __launch_bounds__(256) void ln_kernel(
    const float* __restrict__ X, const float* __restrict__ gamma,
    const float* __restrict__ beta, float* __restrict__ out)
{
    const int row = blockIdx.x;
    const int tid = threadIdx.x;
    const float* x = X + (size_t)row * D_;
    __shared__ float red[256];

    float s = 0.f;
    for (int i = tid; i < D_; i += 256) s += x[i];
    red[tid] = s;
    __syncthreads();
    for (int t = 128; t > 0; t >>= 1) {
        if (tid < t) red[tid] += red[tid + t];
        __syncthreads();
    }
    const float mu = red[0] * (1.f / D_);
    __syncthreads();

    float v = 0.f;
    for (int i = tid; i < D_; i += 256) {
        float t = x[i] - mu;
        v += t * t;
    }
    red[tid] = v;
    __syncthreads();
    for (int t = 128; t > 0; t >>= 1) {
        if (tid < t) red[tid] += red[tid + t];
        __syncthreads();
    }
    const float r = rsqrtf(red[0] * (1.f / D_) + EPS_);

    for (int i = tid; i < D_; i += 256) {
        float o = (x[i] - mu) * r * gamma[i] + beta[i];
        out[(size_t)row * D_ + i] = o;
    }
}

// ---------------------------------------------------------------------------
extern "C" void kernel_launch(void* const* d_in, const int* in_sizes, int n_in,
                              void* d_out, int out_size, void* d_ws, size_t ws_size,
                              hipStream_t stream)
{
    const float* query = (const float*)d_in[0];
    const float* key   = (const float*)d_in[1];
    const float* value = (const float*)d_in[2];
    // d_in[3] = mask (causal) — applied structurally (lower-tri tiles + zero tail)
    const float* wq_w = (const float*)d_in[4];
    const float* wq_b = (const float*)d_in[5];
    const float* wk_w = (const float*)d_in[6];
    const float* wk_b = (const float*)d_in[7];
    const float* wv_w = (const float*)d_in[8];
    const float* wv_b = (const float*)d_in[9];
    const float* wo_w = (const float*)d_in[10];
    const float* wo_b = (const float*)d_in[11];
    const float* ln_g = (const float*)d_in[12];
    const float* ln_b = (const float*)d_in[13];

    float* out_f  = (float*)d_out;                        // (B,S,D)
    float* attn_f = out_f + (size_t)B_ * S_ * D_;         // (B,H,S,S) — also the
                                                          // logits scratch (in-place)

    // Workspace carve-up (bytes): all 256-aligned by construction.
    const size_t NELEM = (size_t)B_ * S_ * D_;            // 4 Mi elements
    const size_t WELEM = (size_t)4 * D_ * D_;             // 4 weight mats
    char* p = (char*)d_ws;
    ushort* Wth = (ushort*)p; p += WELEM * 2;             // 8 MB
    ushort* Wtl = (ushort*)p; p += WELEM * 2;             // 8 MB
    ushort* Qh  = (ushort*)p; p += NELEM * 2;             // 8 MB
    ushort* Ql  = (ushort*)p; p += NELEM * 2;
    ushort* Kh  = (ushort*)p; p += NELEM * 2;
    ushort* Kl  = (ushort*)p; p += NELEM * 2;
    ushort* Vth = (ushort*)p; p += NELEM * 2;             // [b][h][dh][S]
    ushort* Vtl = (ushort*)p; p += NELEM * 2;
    float*  ctx = (float*)p;  p += NELEM * 4;             // 16 MB
    float*  pre = (float*)p;  p += NELEM * 4;             // 16 MB

    // 1) Transpose + split weights -> Wt[n][k] bf16 hi/lo.
    hipLaunchKernelGGL(prep_weights_kernel, dim3(D_ / 32, D_ / 32, 4), dim3(256),
                       0, stream, wq_w, wk_w, wv_w, wo_w, Wth, Wtl);

    // 2) Fused QKV projections (MFMA): Q/K bf16 hi/lo, V transposed per head.
    hipLaunchKernelGGL(gemm_qkv_mfma, dim3(D_ / 128, (B_ * S_) / 128, 3),
                       dim3(256), 0, stream,
                       query, key, value, Wth, Wtl, wq_b, wk_b, wv_b,
                       Qh, Ql, Kh, Kl, Vth, Vtl);

    // Zero ctx for pv's atomic accumulation (stream-ordered, capture-safe).
    hipMemsetAsync(ctx, 0, NELEM * sizeof(float), stream);

    // 3) QK^T (lower-tri 128x128 tiles) -> logits in attn buffer.
    hipLaunchKernelGGL(qk_mfma_kernel, dim3(S_ / 128, S_ / 128, B_ * H_),
                       dim3(256), 0, stream, Qh, Ql, Kh, Kl, attn_f);

    // 4) Row softmax in place (writes normalized probs + zero causal tail).
    hipLaunchKernelGGL(softmax_kernel, dim3(S_, B_ * H_), dim3(256), 0, stream,
                       attn_f);

    // 5) PV (MFMA split-K) -> ctx (B,S,D).
    hipLaunchKernelGGL(pv_mfma_kernel, dim3(S_ / 256, B_ * H_, S_ / 256),
                       dim3(256), 0, stream, attn_f, Vth, Vtl, ctx);

    // 6) Output projection + residual, then LayerNorm.
    hipLaunchKernelGGL(gemm_out_mfma, dim3(D_ / 128, (B_ * S_) / 128),
                       dim3(256), 0, stream,
                       ctx, Wth + (size_t)3 * D_ * D_, Wtl + (size_t)3 * D_ * D_,
                       wo_b, query, pre);

    hipLaunchKernelGGL(ln_kernel, dim3(B_ * S_), dim3(256), 0, stream,
                       pre, ln_g, ln_b, out_f);
}

// Round 4
// 1147.448 us; speedup vs baseline: 3.8790x; 1.0676x over previous
//
#include <hip/hip_runtime.h>

// Problem constants (MultiHeadAttention_14508399526473)
// Inputs fp32 (per reference). Outputs fp32: [out (B,S,D) | attn (B,H,S,S)].
#define B_ 2
#define S_ 2048
#define D_ 1024
#define H_ 16
#define DH_ 64
#define EPS_ 1e-6f

typedef short bf16x8 __attribute__((ext_vector_type(8)));  // 8 bf16 (4 VGPRs)
typedef float f32x4  __attribute__((ext_vector_type(4)));  // MFMA accumulator

// --- bf16 split helpers (RNE). x = hi + lo captures ~16 mantissa bits. ---
__device__ __forceinline__ ushort f2bf(float x) {
    uint u = __float_as_uint(x);
    return (ushort)((u + 0x7fffu + ((u >> 16) & 1u)) >> 16);
}
__device__ __forceinline__ float bf2f(ushort h) {
    return __uint_as_float(((uint)h) << 16);
}
__device__ __forceinline__ void split_bf(float x, ushort& hi, ushort& lo) {
    hi = f2bf(x);
    lo = f2bf(x - bf2f(hi));   // x - hi exact in fp32 (nearby values)
}

// ---------------------------------------------------------------------------
// Weight prep: W[k][n] fp32 -> Wt_hi/Wt_lo[n][k] bf16 (k-contiguous), 4 mats.
// ---------------------------------------------------------------------------
__global__ __launch_bounds__(256) void prep_weights_kernel(
    const float* __restrict__ w0, const float* __restrict__ w1,
    const float* __restrict__ w2, const float* __restrict__ w3,
    ushort* __restrict__ Wth, ushort* __restrict__ Wtl)
{
    const int wi = blockIdx.z;
    const float* W = (wi == 0) ? w0 : (wi == 1) ? w1 : (wi == 2) ? w2 : w3;
    ushort* th = Wth + (size_t)wi * D_ * D_;
    ushort* tl = Wtl + (size_t)wi * D_ * D_;
    const int k0 = blockIdx.x * 32, n0 = blockIdx.y * 32;
    const int tid = threadIdx.x;
    __shared__ float t[32][33];
#pragma unroll
    for (int l = 0; l < 4; ++l) {
        int idx = tid + l * 256;
        int kk = idx >> 5, nn = idx & 31;
        t[kk][nn] = W[(size_t)(k0 + kk) * D_ + n0 + nn];
    }
    __syncthreads();
#pragma unroll
    for (int l = 0; l < 4; ++l) {
        int idx = tid + l * 256;
        int nn = idx >> 5, kk = idx & 31;
        ushort h, lo;
        split_bf(t[kk][nn], h, lo);
        th[(size_t)(n0 + nn) * D_ + k0 + kk] = h;
        tl[(size_t)(n0 + nn) * D_ + k0 + kk] = lo;
    }
}

// ---------------------------------------------------------------------------
// Split-bf16 MFMA GEMM body: C[M,N] = A[M,K] @ B[K,N] (+bias, +residual)
// A fp32, staged+split to LDS. B pre-split bf16 as Bt[n][k] (direct global).
// Block 128x128, 4 waves, each 64x64 = 4x4 frags of 16x16x32.
// MODE 0: fp32 out (+bias,+residual). MODE 1: bf16 hi/lo out [M][N].
// MODE 2: bf16 hi/lo out transposed per head: [b][h][dh][S].
// ---------------------------------------------------------------------------
template <int MODE>
__device__ __forceinline__ void gemm_mfma_body(
    const float* __restrict__ A, const ushort* __restrict__ Bh,
    const ushort* __restrict__ Bl, const float* __restrict__ bias,
    const float* __restrict__ residual, float* __restrict__ Cf,
    ushort* __restrict__ Ch, ushort* __restrict__ Cl,
    int M, int N, int K, int bx, int by)
{
    __shared__ ushort Ah[128][40];   // [m][k], pad 40 shorts (80 B rows)
    __shared__ ushort Al[128][40];

    const int tid = threadIdx.x;
    const int lane = tid & 63, w = tid >> 6;
    const int l15 = lane & 15, l4 = lane >> 4;
    const int row0 = by * 128, col0 = bx * 128;
    const int wm = (w >> 1) * 64, wn = (w & 1) * 64;

    const f32x4 zf = {0.f, 0.f, 0.f, 0.f};
    f32x4 acc[4][4];
#pragma unroll
    for (int i = 0; i < 4; ++i)
#pragma unroll
        for (int j = 0; j < 4; ++j) acc[i][j] = zf;

    for (int k0 = 0; k0 < K; k0 += 32) {
        // Stage A: 128 rows x 32 k fp32 -> hi/lo bf16 LDS.
#pragma unroll
        for (int l = 0; l < 4; ++l) {
            int idx = tid + l * 256;            // 0..1023
            int r = idx >> 3, c4 = (idx & 7) * 4;
            const float4 a = *(const float4*)&A[(size_t)(row0 + r) * K + k0 + c4];
            ushort h0, h1, h2, h3, q0, q1, q2, q3;
            split_bf(a.x, h0, q0); split_bf(a.y, h1, q1);
            split_bf(a.z, h2, q2); split_bf(a.w, h3, q3);
            *(ushort4*)&Ah[r][c4] = make_ushort4(h0, h1, h2, h3);
            *(ushort4*)&Al[r][c4] = make_ushort4(q0, q1, q2, q3);
        }
        // B fragments (global, L2-hot) issued before the barrier.
        bf16x8 bh_[4], bl_[4];
#pragma unroll
        for (int j = 0; j < 4; ++j) {
            const size_t bo = (size_t)(col0 + wn + j * 16 + l15) * K + k0 + l4 * 8;
            bh_[j] = *(const bf16x8*)&Bh[bo];
            bl_[j] = *(const bf16x8*)&Bl[bo];
        }
        __syncthreads();
        bf16x8 ah_[4], al_[4];
#pragma unroll
        for (int i = 0; i < 4; ++i) {
            ah_[i] = *(const bf16x8*)&Ah[wm + i * 16 + l15][l4 * 8];
            al_[i] = *(const bf16x8*)&Al[wm + i * 16 + l15][l4 * 8];
        }
#pragma unroll
        for (int i = 0; i < 4; ++i)
#pragma unroll
            for (int j = 0; j < 4; ++j) {
                acc[i][j] = __builtin_amdgcn_mfma_f32_16x16x32_bf16(
                    ah_[i], bh_[j], acc[i][j], 0, 0, 0);
                acc[i][j] = __builtin_amdgcn_mfma_f32_16x16x32_bf16(
                    ah_[i], bl_[j], acc[i][j], 0, 0, 0);
                acc[i][j] = __builtin_amdgcn_mfma_f32_16x16x32_bf16(
                    al_[i], bh_[j], acc[i][j], 0, 0, 0);
            }
        __syncthreads();
    }

    // Epilogue. D frag: col = l15, row = l4*4 + e (m89-verified layout).
#pragma unroll
    for (int i = 0; i < 4; ++i) {
#pragma unroll
        for (int j = 0; j < 4; ++j) {
            const int col = col0 + wn + j * 16 + l15;
            const float bb = bias[col];
            const int mbase = row0 + wm + i * 16 + l4 * 4;
            if (MODE == 0) {
#pragma unroll
                for (int e = 0; e < 4; ++e) {
                    const int m = mbase + e;
                    float v = acc[i][j][e] + bb;
                    if (residual) v += residual[(size_t)m * N + col];
                    Cf[(size_t)m * N + col] = v;
                }
            } else if (MODE == 1) {
#pragma unroll
                for (int e = 0; e < 4; ++e) {
                    const int m = mbase + e;
                    ushort h, lo;
                    split_bf(acc[i][j][e] + bb, h, lo);
                    Ch[(size_t)m * N + col] = h;
                    Cl[(size_t)m * N + col] = lo;
                }
            } else {
                // Vt: [b][h][dh][S]; 4 consecutive s -> one ushort4 store.
                const int bb_ = mbase / S_;
                const int s0 = mbase - bb_ * S_;
                const int hh = col >> 6, dh = col & 63;
                ushort hv[4], lv[4];
#pragma unroll
                for (int e = 0; e < 4; ++e)
                    split_bf(acc[i][j][e] + bb, hv[e], lv[e]);
                const size_t ofs =
                    (((size_t)bb_ * H_ + hh) * DH_ + dh) * S_ + s0;
                *(ushort4*)&Ch[ofs] = make_ushort4(hv[0], hv[1], hv[2], hv[3]);
                *(ushort4*)&Cl[ofs] = make_ushort4(lv[0], lv[1], lv[2], lv[3]);
            }
        }
    }
}

// Fused QKV projections: z=0 -> Q bf16, z=1 -> K bf16, z=2 -> V transposed.
__global__ __launch_bounds__(256) void gemm_qkv_mfma(
    const float* __restrict__ q, const float* __restrict__ k,
    const float* __restrict__ v,
    const ushort* __restrict__ Wth, const ushort* __restrict__ Wtl,
    const float* __restrict__ bq, const float* __restrict__ bk,
    const float* __restrict__ bv,
    ushort* __restrict__ Qh, ushort* __restrict__ Ql,
    ushort* __restrict__ Kh, ushort* __restrict__ Kl,
    ushort* __restrict__ Vth, ushort* __restrict__ Vtl)
{
    const int z = blockIdx.z;
    const size_t wofs = (size_t)z * D_ * D_;
    if (z == 0)
        gemm_mfma_body<1>(q, Wth, Wtl, bq, nullptr, nullptr, Qh, Ql,
                          B_ * S_, D_, D_, blockIdx.x, blockIdx.y);
    else if (z == 1)
        gemm_mfma_body<1>(k, Wth + wofs, Wtl + wofs, bk, nullptr, nullptr,
                          Kh, Kl, B_ * S_, D_, D_, blockIdx.x, blockIdx.y);
    else
        gemm_mfma_body<2>(v, Wth + wofs, Wtl + wofs, bv, nullptr, nullptr,
                          Vth, Vtl, B_ * S_, D_, D_, blockIdx.x, blockIdx.y);
}

// Output projection: pre = ctx @ wo + bias + residual(query).
__global__ __launch_bounds__(256) void gemm_out_mfma(
    const float* __restrict__ ctx, const ushort* __restrict__ Wth,
    const ushort* __restrict__ Wtl, const float* __restrict__ bias,
    const float* __restrict__ residual, float* __restrict__ pre)
{
    gemm_mfma_body<0>(ctx, Wth, Wtl, bias, residual, pre, nullptr, nullptr,
                      B_ * S_, D_, D_, blockIdx.x, blockIdx.y);
}

// ---------------------------------------------------------------------------
// Fused QK^T + row softmax. One block per (bh, 16-q-row strip); 1024 threads
// (16 waves). Compute phase: wave w MFMAs its 128-key span of S into LDS
// (full strip rows 0..lenmax-1 get covered; no logits ever hit HBM).
// Softmax phase: wave w owns q-row w -- in-wave shuffle max/sum, then
// normalized probs + exact-zero causal tail stream out as float4.
// Arithmetic identical to the previous qk (x0.125) -> softmax(__expf) chain.
// ---------------------------------------------------------------------------
#define RS_ 2056  // LDS row stride in floats (16 rows x 2056 x 4 B = 131.6 KB)

__global__ __launch_bounds__(1024) void qksm_kernel(
    const ushort* __restrict__ Qh, const ushort* __restrict__ Ql,
    const ushort* __restrict__ Kh, const ushort* __restrict__ Kl,
    float* __restrict__ attn)
{
    extern __shared__ float S_lds[];     // [16][RS_]
    const int bh = blockIdx.x;           // x = bh: heads spread across XCDs,
    const int strip = blockIdx.y;        // K(bh) stays L2-resident (~1 MB/head)
    const int b = bh >> 4, h = bh & 15;
    const int s0 = strip * 16;
    const int tid = threadIdx.x;
    const int w = tid >> 6, lane = tid & 63;
    const int l15 = lane & 15, l4 = lane >> 4;
    const int lenmax = s0 + 16;

    // ---- compute phase: wave w covers keys [w*128, w*128+128) ----
    // A-frags: Q rows s0..s0+15 (row = l15, k = l4*8, verified qk layout).
    const size_t qbase = ((size_t)b * S_ + s0 + l15) * D_ + h * DH_ + l4 * 8;
    const bf16x8 ah0 = *(const bf16x8*)&Qh[qbase];
    const bf16x8 ah1 = *(const bf16x8*)&Qh[qbase + 32];
    const bf16x8 al0 = *(const bf16x8*)&Ql[qbase];
    const bf16x8 al1 = *(const bf16x8*)&Ql[qbase + 32];

    for (int jf = 0; jf < 8; ++jf) {
        const int k0 = w * 128 + jf * 16;
        if (k0 >= lenmax) break;         // wave-uniform causal skip
        const size_t kb = ((size_t)b * S_ + k0 + l15) * D_ + h * DH_ + l4 * 8;
        const bf16x8 bh0 = *(const bf16x8*)&Kh[kb];
        const bf16x8 bh1 = *(const bf16x8*)&Kh[kb + 32];
        const bf16x8 bl0 = *(const bf16x8*)&Kl[kb];
        const bf16x8 bl1 = *(const bf16x8*)&Kl[kb + 32];
        f32x4 acc = {0.f, 0.f, 0.f, 0.f};
        acc = __builtin_amdgcn_mfma_f32_16x16x32_bf16(ah0, bh0, acc, 0, 0, 0);
        acc = __builtin_amdgcn_mfma_f32_16x16x32_bf16(ah0, bl0, acc, 0, 0, 0);
        acc = __builtin_amdgcn_mfma_f32_16x16x32_bf16(al0, bh0, acc, 0, 0, 0);
        acc = __builtin_amdgcn_mfma_f32_16x16x32_bf16(ah1, bh1, acc, 0, 0, 0);
        acc = __builtin_amdgcn_mfma_f32_16x16x32_bf16(ah1, bl1, acc, 0, 0, 0);
        acc = __builtin_amdgcn_mfma_f32_16x16x32_bf16(al1, bh1, acc, 0, 0, 0);
        // D layout: row q = l4*4+e, col k = k0 + l15.
#pragma unroll
        for (int e = 0; e < 4; ++e)
            S_lds[(l4 * 4 + e) * RS_ + k0 + l15] = acc[e] * 0.125f;
    }
    __syncthreads();

    // ---- softmax phase: wave w owns q-row w ----
    const int qi = s0 + w;
    const int len = qi + 1;
    const int len4 = (len + 3) >> 2;     // max LDS index read = lenmax-1: safe
    float* Srow = &S_lds[w * RS_];

    float lmax = -INFINITY;
    for (int j4 = lane; j4 < len4; j4 += 64) {
        float4 v = *(const float4*)&Srow[j4 * 4];
        const int j = j4 * 4;
        if (j + 1 >= len) v.y = -INFINITY;
        if (j + 2 >= len) v.z = -INFINITY;
        if (j + 3 >= len) v.w = -INFINITY;
        lmax = fmaxf(fmaxf(lmax, fmaxf(v.x, v.y)), fmaxf(v.z, v.w));
    }
#pragma unroll
    for (int o = 32; o > 0; o >>= 1) lmax = fmaxf(lmax, __shfl_xor(lmax, o));
    const float m = lmax;

    float lsum = 0.f;
    for (int j4 = lane; j4 < len4; j4 += 64) {
        float4 v = *(float4*)&Srow[j4 * 4];
        const int j = j4 * 4;
        float4 e;
        e.x = (j     < len) ? __expf(v.x - m) : 0.f;
        e.y = (j + 1 < len) ? __expf(v.y - m) : 0.f;
        e.z = (j + 2 < len) ? __expf(v.z - m) : 0.f;
        e.w = (j + 3 < len) ? __expf(v.w - m) : 0.f;
        *(float4*)&Srow[j4 * 4] = e;
        lsum += e.x + e.y + e.z + e.w;
    }
#pragma unroll
    for (int o = 32; o > 0; o >>= 1) lsum += __shfl_xor(lsum, o);
    const float inv = 1.f / lsum;

    float4* out4 = (float4*)(attn + ((size_t)bh * S_ + qi) * S_);
    for (int j4 = lane; j4 < S_ / 4; j4 += 64) {
        float4 o = {0.f, 0.f, 0.f, 0.f};
        if (j4 < len4) {
            const float4 e = *(const float4*)&Srow[j4 * 4];
            o.x = e.x * inv; o.y = e.y * inv; o.z = e.z * inv; o.w = e.w * inv;
        }
        out4[j4] = o;
    }
}

// ---------------------------------------------------------------------------
// PV: ctx += attn @ V per (b,h). 256-q-row tiles, split-K (256-key spans),
// fp32 atomics into zeroed ctx. attn split on the fly; Vt direct from L2.
// ---------------------------------------------------------------------------
__global__ __launch_bounds__(256) void pv_mfma_kernel(
    const float* __restrict__ P, const ushort* __restrict__ Vth,
    const ushort* __restrict__ Vtl, float* __restrict__ ctx)
{
    const int tq = blockIdx.x, bh = blockIdx.y, sp = blockIdx.z;
    if (sp > tq) return;                    // keys beyond diagonal: attn == 0
    const int b = bh >> 4, h = bh & 15;
    const int tid = threadIdx.x;
    const int lane = tid & 63, w = tid >> 6;
    const int l15 = lane & 15, l4 = lane >> 4;
    const int wm = w * 64;                  // wave: 64 q-rows x 64 dh

    __shared__ ushort Ph[256][40];
    __shared__ ushort Pl[256][40];

    const float* Arow = P + ((size_t)bh * S_ + (size_t)tq * 256) * S_;
    const size_t vbase = ((size_t)b * H_ + h) * (size_t)DH_ * S_;

    const f32x4 zf = {0.f, 0.f, 0.f, 0.f};
    f32x4 acc[4][4];
#pragma unroll
    for (int i = 0; i < 4; ++i)
#pragma unroll
        for (int j = 0; j < 4; ++j) acc[i][j] = zf;

    const int kb = sp * 256;
    for (int k0 = kb; k0 < kb + 256; k0 += 32) {
#pragma unroll
        for (int l = 0; l < 8; ++l) {
            int idx = tid + l * 256;        // 0..2047
            int r = idx >> 3, c4 = (idx & 7) * 4;
            const float4 a = *(const float4*)&Arow[(size_t)r * S_ + k0 + c4];
            ushort h0, h1, h2, h3, q0, q1, q2, q3;
            split_bf(a.x, h0, q0); split_bf(a.y, h1, q1);
            split_bf(a.z, h2, q2); split_bf(a.w, h3, q3);
            *(ushort4*)&Ph[r][c4] = make_ushort4(h0, h1, h2, h3);
            *(ushort4*)&Pl[r][c4] = make_ushort4(q0, q1, q2, q3);
        }
        bf16x8 bh_[4], bl_[4];
#pragma unroll
        for (int j = 0; j < 4; ++j) {
            const size_t vo = vbase + (size_t)(j * 16 + l15) * S_ + k0 + l4 * 8;
            bh_[j] = *(const bf16x8*)&Vth[vo];
            bl_[j] = *(const bf16x8*)&Vtl[vo];
        }
        __syncthreads();
        bf16x8 ah_[4], al_[4];
#pragma unroll
        for (int i = 0; i < 4; ++i) {
            ah_[i] = *(const bf16x8*)&Ph[wm + i * 16 + l15][l4 * 8];
            al_[i] = *(const bf16x8*)&Pl[wm + i * 16 + l15][l4 * 8];
        }
#pragma unroll
        for (int i = 0; i < 4; ++i)
#pragma unroll
            for (int j = 0; j < 4; ++j) {
                acc[i][j] = __builtin_amdgcn_mfma_f32_16x16x32_bf16(
                    ah_[i], bh_[j], acc[i][j], 0, 0, 0);
                acc[i][j] = __builtin_amdgcn_mfma_f32_16x16x32_bf16(
                    ah_[i], bl_[j], acc[i][j], 0, 0, 0);
                acc[i][j] = __builtin_amdgcn_mfma_f32_16x16x32_bf16(
                    al_[i], bh_[j], acc[i][j], 0, 0, 0);
            }
        __syncthreads();
    }

    float* C = ctx + ((size_t)b * S_ + (size_t)tq * 256 + wm) * D_ + h * DH_;
#pragma unroll
    for (int i = 0; i < 4; ++i)
#pragma unroll
        for (int j = 0; j < 4; ++j) {
            const int col = j * 16 + l15;
#pragma unroll
            for (int e = 0; e < 4; ++e) {
                const int m = i * 16 + l4 * 4 + e;
                atomicAdd(&C[(size_t)m * D_ + col], acc[i][j][e]);
            }
        }
}

// ---------------------------------------------------------------------------
// Row LayerNorm: one block per row of [B*S, D], fp32 in, fp32 out. (verified)
// ---------------------------------------------------------------------------
__global__ __launch_bounds__(256) void ln_kernel(
    const float* __restrict__ X, const float* __restrict__ gamma,
    const float* __restrict__ beta, float* __restrict__ out)
{
    const int row = blockIdx.x;
    const int tid = threadIdx.x;
    const float* x = X + (size_t)row * D_;
    __shared__ float red[256];

    float s = 0.f;
    for (int i = tid; i < D_; i += 256) s += x[i];
    red[tid] = s;
    __syncthreads();
    for (int t = 128; t > 0; t >>= 1) {
        if (tid < t) red[tid] += red[tid + t];
        __syncthreads();
    }
    const float mu = red[0] * (1.f / D_);
    __syncthreads();

    float v = 0.f;
    for (int i = tid; i < D_; i += 256) {
        float t = x[i] - mu;
        v += t * t;
    }
    red[tid] = v;
    __syncthreads();
    for (int t = 128; t > 0; t >>= 1) {
        if (tid < t) red[tid] += red[tid + t];
        __syncthreads();
    }
    const float r = rsqrtf(red[0] * (1.f / D_) + EPS_);

    for (int i = tid; i < D_; i += 256) {
        float o = (x[i] - mu) * r * gamma[i] + beta[i];
        out[(size_t)row * D_ + i] = o;
    }
}

// ---------------------------------------------------------------------------
extern "C" void kernel_launch(void* const* d_in, const int* in_sizes, int n_in,
                              void* d_out, int out_size, void* d_ws, size_t ws_size,
                              hipStream_t stream)
{
    const float* query = (const float*)d_in[0];
    const float* key   = (const float*)d_in[1];
    const float* value = (const float*)d_in[2];
    // d_in[3] = mask (causal) — applied structurally (lower-tri + zero tail)
    const float* wq_w = (const float*)d_in[4];
    const float* wq_b = (const float*)d_in[5];
    const float* wk_w = (const float*)d_in[6];
    const float* wk_b = (const float*)d_in[7];
    const float* wv_w = (const float*)d_in[8];
    const float* wv_b = (const float*)d_in[9];
    const float* wo_w = (const float*)d_in[10];
    const float* wo_b = (const float*)d_in[11];
    const float* ln_g = (const float*)d_in[12];
    const float* ln_b = (const float*)d_in[13];

    float* out_f  = (float*)d_out;                        // (B,S,D)
    float* attn_f = out_f + (size_t)B_ * S_ * D_;         // (B,H,S,S)

    // Workspace carve-up (bytes): all 256-aligned by construction.
    const size_t NELEM = (size_t)B_ * S_ * D_;            // 4 Mi elements
    const size_t WELEM = (size_t)4 * D_ * D_;             // 4 weight mats
    char* p = (char*)d_ws;
    ushort* Wth = (ushort*)p; p += WELEM * 2;             // 8 MB
    ushort* Wtl = (ushort*)p; p += WELEM * 2;             // 8 MB
    ushort* Qh  = (ushort*)p; p += NELEM * 2;             // 8 MB
    ushort* Ql  = (ushort*)p; p += NELEM * 2;
    ushort* Kh  = (ushort*)p; p += NELEM * 2;
    ushort* Kl  = (ushort*)p; p += NELEM * 2;
    ushort* Vth = (ushort*)p; p += NELEM * 2;             // [b][h][dh][S]
    ushort* Vtl = (ushort*)p; p += NELEM * 2;
    float*  ctx = (float*)p;  p += NELEM * 4;             // 16 MB
    float*  pre = (float*)p;  p += NELEM * 4;             // 16 MB

    // 1) Transpose + split weights -> Wt[n][k] bf16 hi/lo.
    hipLaunchKernelGGL(prep_weights_kernel, dim3(D_ / 32, D_ / 32, 4), dim3(256),
                       0, stream, wq_w, wk_w, wv_w, wo_w, Wth, Wtl);

    // 2) Fused QKV projections (MFMA): Q/K bf16 hi/lo, V transposed per head.
    hipLaunchKernelGGL(gemm_qkv_mfma, dim3(D_ / 128, (B_ * S_) / 128, 3),
                       dim3(256), 0, stream,
                       query, key, value, Wth, Wtl, wq_b, wk_b, wv_b,
                       Qh, Ql, Kh, Kl, Vth, Vtl);

    // Zero ctx for pv's atomic accumulation (stream-ordered, capture-safe).
    hipMemsetAsync(ctx, 0, NELEM * sizeof(float), stream);

    // 3) Fused QK^T + softmax -> normalized probs straight to attn buffer
    //    (logits never touch HBM). 131.6 KB dynamic LDS per block.
    hipLaunchKernelGGL(qksm_kernel, dim3(B_ * H_, S_ / 16), dim3(1024),
                       16 * RS_ * sizeof(float), stream,
                       Qh, Ql, Kh, Kl, attn_f);

    // 4) PV (MFMA split-K) -> ctx (B,S,D).
    hipLaunchKernelGGL(pv_mfma_kernel, dim3(S_ / 256, B_ * H_, S_ / 256),
                       dim3(256), 0, stream, attn_f, Vth, Vtl, ctx);

    // 5) Output projection + residual, then LayerNorm.
    hipLaunchKernelGGL(gemm_out_mfma, dim3(D_ / 128, (B_ * S_) / 128),
                       dim3(256), 0, stream,
                       ctx, Wth + (size_t)3 * D_ * D_, Wtl + (size_t)3 * D_ * D_,
                       wo_b, query, pre);

    hipLaunchKernelGGL(ln_kernel, dim3(B_ * S_), dim3(256), 0, stream,
                       pre, ln_g, ln_b, out_f);
}

// Round 5
// 1113.556 us; speedup vs baseline: 3.9970x; 1.0304x over previous
//
#include <hip/hip_runtime.h>

// Problem constants (MultiHeadAttention_14508399526473)
// Inputs fp32 (per reference). Outputs fp32: [out (B,S,D) | attn (B,H,S,S)].
#define B_ 2
#define S_ 2048
#define D_ 1024
#define H_ 16
#define DH_ 64
#define EPS_ 1e-6f

typedef short bf16x8 __attribute__((ext_vector_type(8)));  // 8 bf16 (4 VGPRs)
typedef float f32x4  __attribute__((ext_vector_type(4)));  // MFMA accumulator

// --- bf16 split helpers (RNE). x = hi + lo captures ~16 mantissa bits. ---
__device__ __forceinline__ ushort f2bf(float x) {
    uint u = __float_as_uint(x);
    return (ushort)((u + 0x7fffu + ((u >> 16) & 1u)) >> 16);
}
__device__ __forceinline__ float bf2f(ushort h) {
    return __uint_as_float(((uint)h) << 16);
}
__device__ __forceinline__ void split_bf(float x, ushort& hi, ushort& lo) {
    hi = f2bf(x);
    lo = f2bf(x - bf2f(hi));   // x - hi exact in fp32 (nearby values)
}

// ---------------------------------------------------------------------------
// Weight prep: W[k][n] fp32 -> Wt_hi/Wt_lo[n][k] bf16 (k-contiguous), 4 mats.
// ---------------------------------------------------------------------------
__global__ __launch_bounds__(256) void prep_weights_kernel(
    const float* __restrict__ w0, const float* __restrict__ w1,
    const float* __restrict__ w2, const float* __restrict__ w3,
    ushort* __restrict__ Wth, ushort* __restrict__ Wtl)
{
    const int wi = blockIdx.z;
    const float* W = (wi == 0) ? w0 : (wi == 1) ? w1 : (wi == 2) ? w2 : w3;
    ushort* th = Wth + (size_t)wi * D_ * D_;
    ushort* tl = Wtl + (size_t)wi * D_ * D_;
    const int k0 = blockIdx.x * 32, n0 = blockIdx.y * 32;
    const int tid = threadIdx.x;
    __shared__ float t[32][33];
#pragma unroll
    for (int l = 0; l < 4; ++l) {
        int idx = tid + l * 256;
        int kk = idx >> 5, nn = idx & 31;
        t[kk][nn] = W[(size_t)(k0 + kk) * D_ + n0 + nn];
    }
    __syncthreads();
#pragma unroll
    for (int l = 0; l < 4; ++l) {
        int idx = tid + l * 256;
        int nn = idx >> 5, kk = idx & 31;
        ushort h, lo;
        split_bf(t[kk][nn], h, lo);
        th[(size_t)(n0 + nn) * D_ + k0 + kk] = h;
        tl[(size_t)(n0 + nn) * D_ + k0 + kk] = lo;
    }
}

// ---------------------------------------------------------------------------
// Split-bf16 MFMA GEMM body: C[M,N] = A[M,K] @ B[K,N] (+bias, +residual)
// A fp32, staged+split to LDS. B pre-split bf16 as Bt[n][k] (direct global).
// Block 128x128, 4 waves, each 64x64 = 4x4 frags of 16x16x32.
// MODE 0: fp32 out (+bias,+residual). MODE 1: bf16 hi/lo out [M][N].
// MODE 2: bf16 hi/lo out transposed per head: [b][h][dh][S].
// ---------------------------------------------------------------------------
template <int MODE>
__device__ __forceinline__ void gemm_mfma_body(
    const float* __restrict__ A, const ushort* __restrict__ Bh,
    const ushort* __restrict__ Bl, const float* __restrict__ bias,
    const float* __restrict__ residual, float* __restrict__ Cf,
    ushort* __restrict__ Ch, ushort* __restrict__ Cl,
    int M, int N, int K, int bx, int by)
{
    __shared__ ushort Ah[128][40];   // [m][k], pad 40 shorts (80 B rows)
    __shared__ ushort Al[128][40];

    const int tid = threadIdx.x;
    const int lane = tid & 63, w = tid >> 6;
    const int l15 = lane & 15, l4 = lane >> 4;
    const int row0 = by * 128, col0 = bx * 128;
    const int wm = (w >> 1) * 64, wn = (w & 1) * 64;

    const f32x4 zf = {0.f, 0.f, 0.f, 0.f};
    f32x4 acc[4][4];
#pragma unroll
    for (int i = 0; i < 4; ++i)
#pragma unroll
        for (int j = 0; j < 4; ++j) acc[i][j] = zf;

    for (int k0 = 0; k0 < K; k0 += 32) {
        // Stage A: 128 rows x 32 k fp32 -> hi/lo bf16 LDS.
#pragma unroll
        for (int l = 0; l < 4; ++l) {
            int idx = tid + l * 256;            // 0..1023
            int r = idx >> 3, c4 = (idx & 7) * 4;
            const float4 a = *(const float4*)&A[(size_t)(row0 + r) * K + k0 + c4];
            ushort h0, h1, h2, h3, q0, q1, q2, q3;
            split_bf(a.x, h0, q0); split_bf(a.y, h1, q1);
            split_bf(a.z, h2, q2); split_bf(a.w, h3, q3);
            *(ushort4*)&Ah[r][c4] = make_ushort4(h0, h1, h2, h3);
            *(ushort4*)&Al[r][c4] = make_ushort4(q0, q1, q2, q3);
        }
        // B fragments (global, L2-hot) issued before the barrier.
        bf16x8 bh_[4], bl_[4];
#pragma unroll
        for (int j = 0; j < 4; ++j) {
            const size_t bo = (size_t)(col0 + wn + j * 16 + l15) * K + k0 + l4 * 8;
            bh_[j] = *(const bf16x8*)&Bh[bo];
            bl_[j] = *(const bf16x8*)&Bl[bo];
        }
        __syncthreads();
        bf16x8 ah_[4], al_[4];
#pragma unroll
        for (int i = 0; i < 4; ++i) {
            ah_[i] = *(const bf16x8*)&Ah[wm + i * 16 + l15][l4 * 8];
            al_[i] = *(const bf16x8*)&Al[wm + i * 16 + l15][l4 * 8];
        }
#pragma unroll
        for (int i = 0; i < 4; ++i)
#pragma unroll
            for (int j = 0; j < 4; ++j) {
                acc[i][j] = __builtin_amdgcn_mfma_f32_16x16x32_bf16(
                    ah_[i], bh_[j], acc[i][j], 0, 0, 0);
                acc[i][j] = __builtin_amdgcn_mfma_f32_16x16x32_bf16(
                    ah_[i], bl_[j], acc[i][j], 0, 0, 0);
                acc[i][j] = __builtin_amdgcn_mfma_f32_16x16x32_bf16(
                    al_[i], bh_[j], acc[i][j], 0, 0, 0);
            }
        __syncthreads();
    }

    // Epilogue. D frag: col = l15, row = l4*4 + e (m89-verified layout).
#pragma unroll
    for (int i = 0; i < 4; ++i) {
#pragma unroll
        for (int j = 0; j < 4; ++j) {
            const int col = col0 + wn + j * 16 + l15;
            const float bb = bias[col];
            const int mbase = row0 + wm + i * 16 + l4 * 4;
            if (MODE == 0) {
#pragma unroll
                for (int e = 0; e < 4; ++e) {
                    const int m = mbase + e;
                    float v = acc[i][j][e] + bb;
                    if (residual) v += residual[(size_t)m * N + col];
                    Cf[(size_t)m * N + col] = v;
                }
            } else if (MODE == 1) {
#pragma unroll
                for (int e = 0; e < 4; ++e) {
                    const int m = mbase + e;
                    ushort h, lo;
                    split_bf(acc[i][j][e] + bb, h, lo);
                    Ch[(size_t)m * N + col] = h;
                    Cl[(size_t)m * N + col] = lo;
                }
            } else {
                // Vt: [b][h][dh][S]; 4 consecutive s -> one ushort4 store.
                const int bb_ = mbase / S_;
                const int s0 = mbase - bb_ * S_;
                const int hh = col >> 6, dh = col & 63;
                ushort hv[4], lv[4];
#pragma unroll
                for (int e = 0; e < 4; ++e)
                    split_bf(acc[i][j][e] + bb, hv[e], lv[e]);
                const size_t ofs =
                    (((size_t)bb_ * H_ + hh) * DH_ + dh) * S_ + s0;
                *(ushort4*)&Ch[ofs] = make_ushort4(hv[0], hv[1], hv[2], hv[3]);
                *(ushort4*)&Cl[ofs] = make_ushort4(lv[0], lv[1], lv[2], lv[3]);
            }
        }
    }
}

// Fused QKV projections: z=0 -> Q bf16, z=1 -> K bf16, z=2 -> V transposed.
__global__ __launch_bounds__(256) void gemm_qkv_mfma(
    const float* __restrict__ q, const float* __restrict__ k,
    const float* __restrict__ v,
    const ushort* __restrict__ Wth, const ushort* __restrict__ Wtl,
    const float* __restrict__ bq, const float* __restrict__ bk,
    const float* __restrict__ bv,
    ushort* __restrict__ Qh, ushort* __restrict__ Ql,
    ushort* __restrict__ Kh, ushort* __restrict__ Kl,
    ushort* __restrict__ Vth, ushort* __restrict__ Vtl)
{
    const int z = blockIdx.z;
    const size_t wofs = (size_t)z * D_ * D_;
    if (z == 0)
        gemm_mfma_body<1>(q, Wth, Wtl, bq, nullptr, nullptr, Qh, Ql,
                          B_ * S_, D_, D_, blockIdx.x, blockIdx.y);
    else if (z == 1)
        gemm_mfma_body<1>(k, Wth + wofs, Wtl + wofs, bk, nullptr, nullptr,
                          Kh, Kl, B_ * S_, D_, D_, blockIdx.x, blockIdx.y);
    else
        gemm_mfma_body<2>(v, Wth + wofs, Wtl + wofs, bv, nullptr, nullptr,
                          Vth, Vtl, B_ * S_, D_, D_, blockIdx.x, blockIdx.y);
}

// Output projection: pre = ctx @ wo + bias + residual(query).
__global__ __launch_bounds__(256) void gemm_out_mfma(
    const float* __restrict__ ctx, const ushort* __restrict__ Wth,
    const ushort* __restrict__ Wtl, const float* __restrict__ bias,
    const float* __restrict__ residual, float* __restrict__ pre)
{
    gemm_mfma_body<0>(ctx, Wth, Wtl, bias, residual, pre, nullptr, nullptr,
                      B_ * S_, D_, D_, blockIdx.x, blockIdx.y);
}

// ---------------------------------------------------------------------------
// Fully fused attention middle: QK^T + softmax + PV, one block per
// (bh, 16-q-row strip), 1024 threads (16 waves).
//   P1: wave w MFMAs its 128-key span of scores into LDS.
//   P2: wave w owns q-row w: max/exp/sum (exp'd row back to LDS, zeros padded
//       to a 32-multiple), inv -> shared; streams normalized attn row to HBM.
//   P3: active wave w (w*128 < lenmax) computes PV partial over its own key
//       span: A = P rows from LDS (split-bf16 on the fly), B = Vt[dh][S].
//   P4: wave stashes 16x64 partial into its OWN column region (sole owner).
//   P5: 1024 threads reduce nact partials, scale by inv[row], write ctx.
// No atomics, no ctx memset, attn never re-read from HBM.
// ---------------------------------------------------------------------------
#define RS_ 2052  // LDS row stride in floats (16 x 2052 x 4 B = 131.3 KB)

__global__ __launch_bounds__(1024) void qksm_pv_kernel(
    const ushort* __restrict__ Qh, const ushort* __restrict__ Ql,
    const ushort* __restrict__ Kh, const ushort* __restrict__ Kl,
    const ushort* __restrict__ Vth, const ushort* __restrict__ Vtl,
    float* __restrict__ attn, float* __restrict__ ctx)
{
    extern __shared__ float S_lds[];     // [16][RS_]
    __shared__ float redinv[16];
    const int bh = blockIdx.x;           // x = bh: heads spread across XCDs
    const int strip = blockIdx.y;
    const int b = bh >> 4, h = bh & 15;
    const int s0 = strip * 16;
    const int tid = threadIdx.x;
    const int w = tid >> 6, lane = tid & 63;
    const int l15 = lane & 15, l4 = lane >> 4;
    const int lenmax = s0 + 16;          // multiple of 16

    // ---- P1: scores. A-frags: Q rows s0..s0+15 (row=l15, k=l4*8). ----
    const size_t qbase = ((size_t)b * S_ + s0 + l15) * D_ + h * DH_ + l4 * 8;
    const bf16x8 ah0 = *(const bf16x8*)&Qh[qbase];
    const bf16x8 ah1 = *(const bf16x8*)&Qh[qbase + 32];
    const bf16x8 al0 = *(const bf16x8*)&Ql[qbase];
    const bf16x8 al1 = *(const bf16x8*)&Ql[qbase + 32];

    for (int jf = 0; jf < 8; ++jf) {
        const int k0 = w * 128 + jf * 16;
        if (k0 >= lenmax) break;         // wave-uniform causal skip
        const size_t kb = ((size_t)b * S_ + k0 + l15) * D_ + h * DH_ + l4 * 8;
        const bf16x8 bh0 = *(const bf16x8*)&Kh[kb];
        const bf16x8 bh1 = *(const bf16x8*)&Kh[kb + 32];
        const bf16x8 bl0 = *(const bf16x8*)&Kl[kb];
        const bf16x8 bl1 = *(const bf16x8*)&Kl[kb + 32];
        f32x4 acc = {0.f, 0.f, 0.f, 0.f};
        acc = __builtin_amdgcn_mfma_f32_16x16x32_bf16(ah0, bh0, acc, 0, 0, 0);
        acc = __builtin_amdgcn_mfma_f32_16x16x32_bf16(ah0, bl0, acc, 0, 0, 0);
        acc = __builtin_amdgcn_mfma_f32_16x16x32_bf16(al0, bh0, acc, 0, 0, 0);
        acc = __builtin_amdgcn_mfma_f32_16x16x32_bf16(ah1, bh1, acc, 0, 0, 0);
        acc = __builtin_amdgcn_mfma_f32_16x16x32_bf16(ah1, bl1, acc, 0, 0, 0);
        acc = __builtin_amdgcn_mfma_f32_16x16x32_bf16(al1, bh1, acc, 0, 0, 0);
        // D layout: row q = l4*4+e, col k = k0 + l15.
#pragma unroll
        for (int e = 0; e < 4; ++e)
            S_lds[(l4 * 4 + e) * RS_ + k0 + l15] = acc[e] * 0.125f;
    }
    __syncthreads();

    // ---- P2: softmax, wave w owns q-row w ----
    const int qi = s0 + w;
    const int len = qi + 1;
    const int len4 = (len + 3) >> 2;
    const int Zf4 = ((lenmax + 31) & ~31) >> 2;   // exp/zero bound (32-pad)
    float* Srow = &S_lds[w * RS_];

    float lmax = -INFINITY;
    for (int j4 = lane; j4 < len4; j4 += 64) {
        float4 v = *(const float4*)&Srow[j4 * 4];
        const int j = j4 * 4;
        if (j + 1 >= len) v.y = -INFINITY;
        if (j + 2 >= len) v.z = -INFINITY;
        if (j + 3 >= len) v.w = -INFINITY;
        lmax = fmaxf(fmaxf(lmax, fmaxf(v.x, v.y)), fmaxf(v.z, v.w));
    }
#pragma unroll
    for (int o = 32; o > 0; o >>= 1) lmax = fmaxf(lmax, __shfl_xor(lmax, o));
    const float m = lmax;

    float lsum = 0.f;
    for (int j4 = lane; j4 < Zf4; j4 += 64) {     // exp + zero-pad to 32-mult
        float4 v = *(float4*)&Srow[j4 * 4];
        const int j = j4 * 4;
        float4 e;
        e.x = (j     < len) ? __expf(v.x - m) : 0.f;
        e.y = (j + 1 < len) ? __expf(v.y - m) : 0.f;
        e.z = (j + 2 < len) ? __expf(v.z - m) : 0.f;
        e.w = (j + 3 < len) ? __expf(v.w - m) : 0.f;
        *(float4*)&Srow[j4 * 4] = e;
        lsum += e.x + e.y + e.z + e.w;
    }
#pragma unroll
    for (int o = 32; o > 0; o >>= 1) lsum += __shfl_xor(lsum, o);
    const float inv = 1.f / lsum;
    if (lane == 0) redinv[w] = inv;

    // attn row out: normalized probs + exact-zero causal tail.
    const int Lmax4 = lenmax >> 2;
    float4* out4 = (float4*)(attn + ((size_t)bh * S_ + qi) * S_);
    for (int j4 = lane; j4 < S_ / 4; j4 += 64) {
        float4 o = {0.f, 0.f, 0.f, 0.f};
        if (j4 < Lmax4) {
            const float4 e = *(const float4*)&Srow[j4 * 4];
            o.x = e.x * inv; o.y = e.y * inv; o.z = e.z * inv; o.w = e.w * inv;
        }
        out4[j4] = o;
    }
    __syncthreads();   // all exp rows + redinv visible to all waves

    // ---- P3: PV partial over this wave's own key span ----
    const int nact = strip / 8 + 1;    // waves with w*128 < lenmax
    const f32x4 zf = {0.f, 0.f, 0.f, 0.f};
    f32x4 pacc[4] = {zf, zf, zf, zf};
    if (w < nact) {
        const size_t vbase = ((size_t)b * H_ + h) * (size_t)DH_ * S_;
        for (int c = 0; c < 4; ++c) {
            const int k0 = w * 128 + c * 32;
            if (k0 >= lenmax) break;   // zero-pad guarantees full-32 validity
            // A-frag: P[q=l15][k0 + l4*8 .. +8] fp32 -> split bf16.
            const float* prow = &S_lds[l15 * RS_ + k0 + l4 * 8];
            const float4 p0 = *(const float4*)&prow[0];
            const float4 p1 = *(const float4*)&prow[4];
            bf16x8 pah, pal;
            {
                ushort hh, ll;
                split_bf(p0.x, hh, ll); pah[0] = (short)hh; pal[0] = (short)ll;
                split_bf(p0.y, hh, ll); pah[1] = (short)hh; pal[1] = (short)ll;
                split_bf(p0.z, hh, ll); pah[2] = (short)hh; pal[2] = (short)ll;
                split_bf(p0.w, hh, ll); pah[3] = (short)hh; pal[3] = (short)ll;
                split_bf(p1.x, hh, ll); pah[4] = (short)hh; pal[4] = (short)ll;
                split_bf(p1.y, hh, ll); pah[5] = (short)hh; pal[5] = (short)ll;
                split_bf(p1.z, hh, ll); pah[6] = (short)hh; pal[6] = (short)ll;
                split_bf(p1.w, hh, ll); pah[7] = (short)hh; pal[7] = (short)ll;
            }
#pragma unroll
            for (int j = 0; j < 4; ++j) {
                const size_t vo = vbase + (size_t)(j * 16 + l15) * S_ + k0 + l4 * 8;
                const bf16x8 vh = *(const bf16x8*)&Vth[vo];
                const bf16x8 vl = *(const bf16x8*)&Vtl[vo];
                pacc[j] = __builtin_amdgcn_mfma_f32_16x16x32_bf16(
                    pah, vh, pacc[j], 0, 0, 0);
                pacc[j] = __builtin_amdgcn_mfma_f32_16x16x32_bf16(
                    pah, vl, pacc[j], 0, 0, 0);
                pacc[j] = __builtin_amdgcn_mfma_f32_16x16x32_bf16(
                    pal, vh, pacc[j], 0, 0, 0);
            }
        }
        // ---- P4: stash partial into OWN column region (sole owner). ----
        // D layout: row q = l4*4+e, col dh = j*16+l15.
#pragma unroll
        for (int j = 0; j < 4; ++j)
#pragma unroll
            for (int e = 0; e < 4; ++e)
                S_lds[(l4 * 4 + e) * RS_ + w * 128 + j * 16 + l15] = pacc[j][e];
    }
    __syncthreads();

    // ---- P5: reduce partials, scale by inv[row], write ctx (coalesced). ----
    const int r5 = tid >> 6, dh5 = tid & 63;
    float s5 = 0.f;
    for (int ww = 0; ww < nact; ++ww)
        s5 += S_lds[r5 * RS_ + ww * 128 + dh5];
    ctx[((size_t)b * S_ + s0 + r5) * D_ + h * DH_ + dh5] = s5 * redinv[r5];
}

// ---------------------------------------------------------------------------
// Row LayerNorm: one block per row of [B*S, D], fp32 in, fp32 out. (verified)
// ---------------------------------------------------------------------------
__global__ __launch_bounds__(256) void ln_kernel(
    const float* __restrict__ X, const float* __restrict__ gamma,
    const float* __restrict__ beta, float* __restrict__ out)
{
    const int row = blockIdx.x;
    const int tid = threadIdx.x;
    const float* x = X + (size_t)row * D_;
    __shared__ float red[256];

    float s = 0.f;
    for (int i = tid; i < D_; i += 256) s += x[i];
    red[tid] = s;
    __syncthreads();
    for (int t = 128; t > 0; t >>= 1) {
        if (tid < t) red[tid] += red[tid + t];
        __syncthreads();
    }
    const float mu = red[0] * (1.f / D_);
    __syncthreads();

    float v = 0.f;
    for (int i = tid; i < D_; i += 256) {
        float t = x[i] - mu;
        v += t * t;
    }
    red[tid] = v;
    __syncthreads();
    for (int t = 128; t > 0; t >>= 1) {
        if (tid < t) red[tid] += red[tid + t];
        __syncthreads();
    }
    const float r = rsqrtf(red[0] * (1.f / D_) + EPS_);

    for (int i = tid; i < D_; i += 256) {
        float o = (x[i] - mu) * r * gamma[i] + beta[i];
        out[(size_t)row * D_ + i] = o;
    }
}

// ---------------------------------------------------------------------------
extern "C" void kernel_launch(void* const* d_in, const int* in_sizes, int n_in,
                              void* d_out, int out_size, void* d_ws, size_t ws_size,
                              hipStream_t stream)
{
    const float* query = (const float*)d_in[0];
    const float* key   = (const float*)d_in[1];
    const float* value = (const float*)d_in[2];
    // d_in[3] = mask (causal) — applied structurally (lower-tri + zero tail)
    const float* wq_w = (const float*)d_in[4];
    const float* wq_b = (const float*)d_in[5];
    const float* wk_w = (const float*)d_in[6];
    const float* wk_b = (const float*)d_in[7];
    const float* wv_w = (const float*)d_in[8];
    const float* wv_b = (const float*)d_in[9];
    const float* wo_w = (const float*)d_in[10];
    const float* wo_b = (const float*)d_in[11];
    const float* ln_g = (const float*)d_in[12];
    const float* ln_b = (const float*)d_in[13];

    float* out_f  = (float*)d_out;                        // (B,S,D)
    float* attn_f = out_f + (size_t)B_ * S_ * D_;         // (B,H,S,S)

    // Workspace carve-up (bytes): all 256-aligned by construction.
    const size_t NELEM = (size_t)B_ * S_ * D_;            // 4 Mi elements
    const size_t WELEM = (size_t)4 * D_ * D_;             // 4 weight mats
    char* p = (char*)d_ws;
    ushort* Wth = (ushort*)p; p += WELEM * 2;             // 8 MB
    ushort* Wtl = (ushort*)p; p += WELEM * 2;             // 8 MB
    ushort* Qh  = (ushort*)p; p += NELEM * 2;             // 8 MB
    ushort* Ql  = (ushort*)p; p += NELEM * 2;
    ushort* Kh  = (ushort*)p; p += NELEM * 2;
    ushort* Kl  = (ushort*)p; p += NELEM * 2;
    ushort* Vth = (ushort*)p; p += NELEM * 2;             // [b][h][dh][S]
    ushort* Vtl = (ushort*)p; p += NELEM * 2;
    float*  ctx = (float*)p;  p += NELEM * 4;             // 16 MB
    float*  pre = (float*)p;  p += NELEM * 4;             // 16 MB

    // 1) Transpose + split weights -> Wt[n][k] bf16 hi/lo.
    hipLaunchKernelGGL(prep_weights_kernel, dim3(D_ / 32, D_ / 32, 4), dim3(256),
                       0, stream, wq_w, wk_w, wv_w, wo_w, Wth, Wtl);

    // 2) Fused QKV projections (MFMA): Q/K bf16 hi/lo, V transposed per head.
    hipLaunchKernelGGL(gemm_qkv_mfma, dim3(D_ / 128, (B_ * S_) / 128, 3),
                       dim3(256), 0, stream,
                       query, key, value, Wth, Wtl, wq_b, wk_b, wv_b,
                       Qh, Ql, Kh, Kl, Vth, Vtl);

    // 3) Fully fused attention middle: QK^T + softmax + PV.
    //    attn probs to HBM once; ctx written directly (no atomics/memset).
    hipLaunchKernelGGL(qksm_pv_kernel, dim3(B_ * H_, S_ / 16), dim3(1024),
                       16 * RS_ * sizeof(float), stream,
                       Qh, Ql, Kh, Kl, Vth, Vtl, attn_f, ctx);

    // 4) Output projection + residual, then LayerNorm.
    hipLaunchKernelGGL(gemm_out_mfma, dim3(D_ / 128, (B_ * S_) / 128),
                       dim3(256), 0, stream,
                       ctx, Wth + (size_t)3 * D_ * D_, Wtl + (size_t)3 * D_ * D_,
                       wo_b, query, pre);

    hipLaunchKernelGGL(ln_kernel, dim3(B_ * S_), dim3(256), 0, stream,
                       pre, ln_g, ln_b, out_f);
}